// Round 8
// baseline (428.141 us; speedup 1.0000x reference)
//
#include <hip/hip_runtime.h>
#include <hip/hip_bf16.h>

typedef __bf16 bf16;
typedef __bf16 bf16x8 __attribute__((ext_vector_type(8)));
typedef __bf16 bf16x4 __attribute__((ext_vector_type(4)));
typedef __bf16 bf16x2 __attribute__((ext_vector_type(2)));
typedef float f32x4 __attribute__((ext_vector_type(4)));

#define CAP 48  // padded-CSR capacity; deg ~ Poisson(10), P(deg>=48) ~ 1e-18/node

__device__ __forceinline__ float b2f(bf16 v) { return (float)v; }
__device__ __forceinline__ bf16 f2b(float v) { return (bf16)v; }

__device__ __forceinline__ float leaky(float x) { return fmaxf(x, 0.2f * x); }

__device__ __forceinline__ bf16x8 zero8() {
    bf16x8 v;
    #pragma unroll
    for (int j = 0; j < 8; ++j) v[j] = (bf16)0.0f;
    return v;
}

// ---------------- weight pre-swizzle into MFMA fragment layout (bf16) ------
// frag f=(kb,nt,ln): dst[f*8+j] = W[kb*32 + (ln>>4)*8 + j][nt*16 + (ln&15)]
__device__ __forceinline__ void swizzle_one(const float* __restrict__ W, bf16* __restrict__ dst,
                                            int f, int NT, int Kreal, int C) {
    int kb = f / (NT * 64);
    int rem = f % (NT * 64);
    int nt = rem / 64;
    int ln = rem % 64;
    int q = ln >> 4, m = ln & 15;
    int c = nt * 16 + m;
    bf16x8 v;
    #pragma unroll
    for (int j = 0; j < 8; ++j) {
        int k = kb * 32 + q * 8 + j;
        v[j] = (k < Kreal) ? f2b(W[k * C + c]) : (bf16)0.0f;
    }
    *reinterpret_cast<bf16x8*>(dst + f * 8) = v;
}

// ---------------- kernel 1: padded-CSR scatter + weight swizzle ------------
// h0-build has moved into the layer-1 GEMM (LDS A-tile); this kernel is the
// transaction-bound scatter (1 edge/thread, NT stores avoid cross-XCD RFO
// ping-pong) plus 49 blocks of weight swizzle (runs first, finishes early).
__global__ void scatter_kernel(const int* __restrict__ e_src, const int* __restrict__ e_dst,
                               int* __restrict__ cnt, int* __restrict__ colidx, int e,
                               const float* __restrict__ W1, const float* __restrict__ Wl1,
                               const float* __restrict__ W2, const float* __restrict__ Wl2,
                               const float* __restrict__ Wm1,
                               bf16* __restrict__ w1s, bf16* __restrict__ wl1s,
                               bf16* __restrict__ w2s, bf16* __restrict__ wl2s,
                               bf16* __restrict__ wm1s) {
    int bid = blockIdx.x;
    if (bid < 49) {  // 12544 fragments / 256 = 49 blocks exactly
        int g = bid * blockDim.x + threadIdx.x;
        if (g < 3072)        swizzle_one(W1,  w1s,  g,          8, 192, 128);
        else if (g < 6144)   swizzle_one(Wl1, wl1s, g - 3072,   8, 192, 128);
        else if (g < 8192)   swizzle_one(W2,  w2s,  g - 6144,   8, 128, 128);
        else if (g < 10240)  swizzle_one(Wl2, wl2s, g - 8192,   8, 128, 128);
        else if (g < 12544)  swizzle_one(Wm1, wm1s, g - 10240,  4, 257,  64);
        return;
    }
    int i = (bid - 49) * blockDim.x + threadIdx.x;
    if (i < e) {
        int d = __builtin_nontemporal_load(e_dst + i);
        int s = __builtin_nontemporal_load(e_src + i);
        int k = atomicAdd(&cnt[d], 1);
        if (k < CAP) __builtin_nontemporal_store(s, colidx + d * CAP + k);
    }
}

// ---------------- layer-1 GEMM with fused h0 build (LDS A-tile) ------------
// Block (256 thr) covers 64 rows x 128 cols. Build phase: 8 rows in parallel
// (32 lanes/row) x 8 iters -> sH[64][200] bf16 (400B stride: <=2-way LDS
// aliasing on ds_read_b128, free). h0 never touches HBM (saves 38.4MB write
// + 38.4MB read vs materialized h0). Numerics identical: same f2b roundings.
template <int KB>
__global__ __launch_bounds__(256) void gemm_l1_kernel(
    const float* __restrict__ x,
    const float* __restrict__ gene_table,
    const int* __restrict__ pos,
    const bf16* __restrict__ Wg, const bf16* __restrict__ Wl,
    const float* __restrict__ bias_l,
    bf16* __restrict__ outg, bf16* __restrict__ outl, int ldo, int nrows,
    const float* __restrict__ attn_s, const float* __restrict__ attn_d,
    float* __restrict__ asrc, float* __restrict__ adst) {
    const int NTT = 8;  // total col tiles
    __shared__ bf16 sH[64][200];
    __shared__ float sA[64][2];
    int tid = threadIdx.x;

    // ---- build A-tile (h0 rows) into LDS ----
    {
        int rsub = tid >> 5, l32 = tid & 31;
        #pragma unroll
        for (int rr = 0; rr < 8; ++rr) {
            int rloc = rr * 8 + rsub;
            long long row = (long long)blockIdx.x * 64 + rloc;
            if (row < nrows) {
                const float* g = gene_table + (long long)pos[row] * 128;
                float4 p = reinterpret_cast<const float4*>(g)[l32];
                float ss = p.x * p.x + p.y * p.y + p.z * p.z + p.w * p.w;
                #pragma unroll
                for (int o = 16; o; o >>= 1) ss += __shfl_xor(ss, o, 32);
                float nrm = sqrtf(ss);
                float sc = nrm > 1.0f ? 1.0f / (nrm + 1e-7f) : 1.0f;
                float2 xv = reinterpret_cast<const float2*>(x + row * 64)[l32];
                sH[rloc][2 * l32]     = f2b(xv.x);
                sH[rloc][2 * l32 + 1] = f2b(xv.y);
                sH[rloc][64 + 4 * l32 + 0] = f2b(p.x * sc);
                sH[rloc][64 + 4 * l32 + 1] = f2b(p.y * sc);
                sH[rloc][64 + 4 * l32 + 2] = f2b(p.z * sc);
                sH[rloc][64 + 4 * l32 + 3] = f2b(p.w * sc);
            } else {  // zero-fill tail rows so MFMA reads are clean
                sH[rloc][2 * l32]     = (bf16)0.0f;
                sH[rloc][2 * l32 + 1] = (bf16)0.0f;
                sH[rloc][64 + 4 * l32 + 0] = (bf16)0.0f;
                sH[rloc][64 + 4 * l32 + 1] = (bf16)0.0f;
                sH[rloc][64 + 4 * l32 + 2] = (bf16)0.0f;
                sH[rloc][64 + 4 * l32 + 3] = (bf16)0.0f;
            }
        }
    }
    __syncthreads();

    int wave = tid >> 6, lane = tid & 63;
    int q = lane >> 4, m = lane & 15;
    int nt0 = (wave & 1) * 4;
    int r0loc = (wave >> 1) * 32 + m;
    long long row_base = (long long)blockIdx.x * 64 + (wave >> 1) * 32;
    long long r0 = row_base + m;
    long long r1 = row_base + 16 + m;

    f32x4 accg[2][4], accl[2][4];
    #pragma unroll
    for (int t = 0; t < 2; ++t)
        #pragma unroll
        for (int nt = 0; nt < 4; ++nt) {
            f32x4 z = {0.f, 0.f, 0.f, 0.f};
            accg[t][nt] = z; accl[t][nt] = z;
        }

    #pragma unroll
    for (int kb = 0; kb < KB; ++kb) {
        bf16x8 b0 = *reinterpret_cast<const bf16x8*>(&sH[r0loc][kb * 32 + q * 8]);
        bf16x8 b1 = *reinterpret_cast<const bf16x8*>(&sH[r0loc + 16][kb * 32 + q * 8]);
        #pragma unroll
        for (int nt = 0; nt < 4; ++nt) {
            bf16x8 wg = *reinterpret_cast<const bf16x8*>(Wg + ((kb * NTT + nt0 + nt) * 64 + lane) * 8);
            bf16x8 wl = *reinterpret_cast<const bf16x8*>(Wl + ((kb * NTT + nt0 + nt) * 64 + lane) * 8);
            accg[0][nt] = __builtin_amdgcn_mfma_f32_16x16x32_bf16(wg, b0, accg[0][nt], 0, 0, 0);
            accg[1][nt] = __builtin_amdgcn_mfma_f32_16x16x32_bf16(wg, b1, accg[1][nt], 0, 0, 0);
            accl[0][nt] = __builtin_amdgcn_mfma_f32_16x16x32_bf16(wl, b0, accl[0][nt], 0, 0, 0);
            accl[1][nt] = __builtin_amdgcn_mfma_f32_16x16x32_bf16(wl, b1, accl[1][nt], 0, 0, 0);
        }
    }
    #pragma unroll
    for (int t = 0; t < 2; ++t) {
        long long row = t ? r1 : r0;
        if (row < nrows) {
            #pragma unroll
            for (int nt = 0; nt < 4; ++nt) {
                int c0 = (nt0 + nt) * 16 + q * 4;
                bf16x4 og, ol;
                #pragma unroll
                for (int r = 0; r < 4; ++r) {
                    og[r] = f2b(accg[t][nt][r]);
                    ol[r] = f2b(accl[t][nt][r] + bias_l[c0 + r]);
                }
                *reinterpret_cast<bf16x4*>(outg + row * ldo + c0) = og;
                *reinterpret_cast<bf16x4*>(outl + row * ldo + c0) = ol;
            }
        }
    }
    float svt[2], dvt[2];
    #pragma unroll
    for (int t = 0; t < 2; ++t) {
        float sv = 0.f, dv = 0.f;
        #pragma unroll
        for (int nt = 0; nt < 4; ++nt) {
            int c0 = (nt0 + nt) * 16 + q * 4;
            #pragma unroll
            for (int r = 0; r < 4; ++r) {
                float v = accg[t][nt][r];
                sv = fmaf(v, attn_s[c0 + r], sv);
                dv = fmaf(v, attn_d[c0 + r], dv);
            }
        }
        sv += __shfl_xor(sv, 16); sv += __shfl_xor(sv, 32);
        dv += __shfl_xor(dv, 16); dv += __shfl_xor(dv, 32);
        svt[t] = sv; dvt[t] = dv;
        if ((wave & 1) == 0 && q == 0) {
            int rloc = (wave >> 1) * 32 + t * 16 + m;
            sA[rloc][0] = sv; sA[rloc][1] = dv;
        }
    }
    __syncthreads();
    #pragma unroll
    for (int t = 0; t < 2; ++t) {
        long long row = t ? r1 : r0;
        if ((wave & 1) == 1 && q == 0 && row < nrows) {
            int rloc = (wave >> 1) * 32 + t * 16 + m;
            asrc[row] = svt[t] + sA[rloc][0];
            adst[row] = dvt[t] + sA[rloc][1];
        }
    }
}

// ---------------- dual GEMM (layer 2), column-split across waves -----------
template <int KB>
__global__ __launch_bounds__(256) void gemm_dual_kernel(
    const bf16* __restrict__ A, int lda,
    const bf16* __restrict__ Wg, const bf16* __restrict__ Wl,
    const float* __restrict__ bias_l,
    bf16* __restrict__ outg, bf16* __restrict__ outl, int ldo, int nrows,
    const float* __restrict__ attn_s, const float* __restrict__ attn_d,
    float* __restrict__ asrc, float* __restrict__ adst) {
    const int NTT = 8;  // total col tiles
    __shared__ float sA[64][2];
    int tid = threadIdx.x;
    int wave = tid >> 6, lane = tid & 63;
    int q = lane >> 4, m = lane & 15;
    int nt0 = (wave & 1) * 4;
    long long row_base = (long long)blockIdx.x * 64 + (wave >> 1) * 32;
    long long r0 = row_base + m;
    long long r1 = row_base + 16 + m;
    bool v0 = r0 < nrows, v1 = r1 < nrows;

    f32x4 accg[2][4], accl[2][4];
    #pragma unroll
    for (int t = 0; t < 2; ++t)
        #pragma unroll
        for (int nt = 0; nt < 4; ++nt) {
            f32x4 z = {0.f, 0.f, 0.f, 0.f};
            accg[t][nt] = z; accl[t][nt] = z;
        }

    bf16x8 b0 = v0 ? *reinterpret_cast<const bf16x8*>(A + r0 * lda + q * 8) : zero8();
    bf16x8 b1 = v1 ? *reinterpret_cast<const bf16x8*>(A + r1 * lda + q * 8) : zero8();
    #pragma unroll
    for (int kb = 0; kb < KB; ++kb) {
        bf16x8 nb0, nb1;
        if (kb + 1 < KB) {
            nb0 = v0 ? *reinterpret_cast<const bf16x8*>(A + r0 * lda + (kb + 1) * 32 + q * 8) : zero8();
            nb1 = v1 ? *reinterpret_cast<const bf16x8*>(A + r1 * lda + (kb + 1) * 32 + q * 8) : zero8();
        }
        #pragma unroll
        for (int nt = 0; nt < 4; ++nt) {
            bf16x8 wg = *reinterpret_cast<const bf16x8*>(Wg + ((kb * NTT + nt0 + nt) * 64 + lane) * 8);
            bf16x8 wl = *reinterpret_cast<const bf16x8*>(Wl + ((kb * NTT + nt0 + nt) * 64 + lane) * 8);
            accg[0][nt] = __builtin_amdgcn_mfma_f32_16x16x32_bf16(wg, b0, accg[0][nt], 0, 0, 0);
            accg[1][nt] = __builtin_amdgcn_mfma_f32_16x16x32_bf16(wg, b1, accg[1][nt], 0, 0, 0);
            accl[0][nt] = __builtin_amdgcn_mfma_f32_16x16x32_bf16(wl, b0, accl[0][nt], 0, 0, 0);
            accl[1][nt] = __builtin_amdgcn_mfma_f32_16x16x32_bf16(wl, b1, accl[1][nt], 0, 0, 0);
        }
        b0 = nb0; b1 = nb1;
    }
    #pragma unroll
    for (int t = 0; t < 2; ++t) {
        long long row = t ? r1 : r0;
        if (row < nrows) {
            #pragma unroll
            for (int nt = 0; nt < 4; ++nt) {
                int c0 = (nt0 + nt) * 16 + q * 4;
                bf16x4 og, ol;
                #pragma unroll
                for (int r = 0; r < 4; ++r) {
                    og[r] = f2b(accg[t][nt][r]);
                    ol[r] = f2b(accl[t][nt][r] + bias_l[c0 + r]);
                }
                *reinterpret_cast<bf16x4*>(outg + row * ldo + c0) = og;
                *reinterpret_cast<bf16x4*>(outl + row * ldo + c0) = ol;
            }
        }
    }
    float svt[2], dvt[2];
    #pragma unroll
    for (int t = 0; t < 2; ++t) {
        float sv = 0.f, dv = 0.f;
        #pragma unroll
        for (int nt = 0; nt < 4; ++nt) {
            int c0 = (nt0 + nt) * 16 + q * 4;
            #pragma unroll
            for (int r = 0; r < 4; ++r) {
                float v = accg[t][nt][r];
                sv = fmaf(v, attn_s[c0 + r], sv);
                dv = fmaf(v, attn_d[c0 + r], dv);
            }
        }
        sv += __shfl_xor(sv, 16); sv += __shfl_xor(sv, 32);
        dv += __shfl_xor(dv, 16); dv += __shfl_xor(dv, 32);
        svt[t] = sv; dvt[t] = dv;
        if ((wave & 1) == 0 && q == 0) {
            int rloc = (wave >> 1) * 32 + t * 16 + m;
            sA[rloc][0] = sv; sA[rloc][1] = dv;
        }
    }
    __syncthreads();
    #pragma unroll
    for (int t = 0; t < 2; ++t) {
        long long row = t ? r1 : r0;
        if ((wave & 1) == 1 && q == 0 && row < nrows) {
            int rloc = (wave >> 1) * 32 + t * 16 + m;
            asrc[row] = svt[t] + sA[rloc][0];
            adst[row] = dvt[t] + sA[rloc][1];
        }
    }
}

// ---------------- MLP GEMM: out = relu(relu(A@Wm1+bm1)@Wm2+bm2) ------------
template <int KB, int NT>
__global__ __launch_bounds__(256) void gemm_mlp_kernel(
    const bf16* __restrict__ A, int lda,
    const bf16* __restrict__ Wsw,
    const float* __restrict__ bias, int nrows,
    const float* __restrict__ Wm2, const float* __restrict__ bm2,
    float* __restrict__ out_final) {
    int tid = threadIdx.x;
    int wave = tid >> 6, lane = tid & 63;
    int q = lane >> 4, m = lane & 15;
    long long row_base = (long long)blockIdx.x * 128 + wave * 32;
    long long r0 = row_base + m;
    long long r1 = row_base + 16 + m;
    bool v0 = r0 < nrows, v1 = r1 < nrows;

    f32x4 acc[2][NT];
    #pragma unroll
    for (int t = 0; t < 2; ++t)
        #pragma unroll
        for (int nt = 0; nt < NT; ++nt) {
            f32x4 z = {0.f, 0.f, 0.f, 0.f};
            acc[t][nt] = z;
        }

    bf16x8 b0 = v0 ? *reinterpret_cast<const bf16x8*>(A + r0 * lda + q * 8) : zero8();
    bf16x8 b1 = v1 ? *reinterpret_cast<const bf16x8*>(A + r1 * lda + q * 8) : zero8();
    #pragma unroll
    for (int kb = 0; kb < KB; ++kb) {
        bf16x8 nb0, nb1;
        if (kb + 1 < KB) {
            nb0 = v0 ? *reinterpret_cast<const bf16x8*>(A + r0 * lda + (kb + 1) * 32 + q * 8) : zero8();
            nb1 = v1 ? *reinterpret_cast<const bf16x8*>(A + r1 * lda + (kb + 1) * 32 + q * 8) : zero8();
        }
        #pragma unroll
        for (int nt = 0; nt < NT; ++nt) {
            bf16x8 w = *reinterpret_cast<const bf16x8*>(Wsw + ((kb * NT + nt) * 64 + lane) * 8);
            acc[0][nt] = __builtin_amdgcn_mfma_f32_16x16x32_bf16(w, b0, acc[0][nt], 0, 0, 0);
            acc[1][nt] = __builtin_amdgcn_mfma_f32_16x16x32_bf16(w, b1, acc[1][nt], 0, 0, 0);
        }
        b0 = nb0; b1 = nb1;
    }
    #pragma unroll
    for (int t = 0; t < 2; ++t) {
        float sv = 0.f;
        #pragma unroll
        for (int nt = 0; nt < NT; ++nt) {
            int c0 = nt * 16 + q * 4;
            #pragma unroll
            for (int r = 0; r < 4; ++r) {
                float v = fmaxf(acc[t][nt][r] + bias[c0 + r], 0.0f);
                sv = fmaf(v, Wm2[c0 + r], sv);
            }
        }
        sv += __shfl_xor(sv, 16); sv += __shfl_xor(sv, 32);
        long long row = t ? r1 : r0;
        if (q == 0 && row < nrows) out_final[row] = fmaxf(sv + bm2[0], 0.0f);
    }
}

// ---------------- GAT aggregation: 2 nodes/wave, 32 lanes/node -------------
// Padded CSR (CAP slots/node, cnt[d] valid). Each 32-lane group owns one
// node; lane handles 4 channels (bf16x4 = 8 B loads). Invalid lanes carry
// wj=0 / sj=d, so FULL 4-wide iterations over padded slots are bit-exact:
// no serial remainder loop (for deg~10 the tail was ~half the iterations).
// Slot 1 (j = 32+lane) covers the statistically-cold 32 < deg <= CAP tail.
__global__ void gat_edge_kernel(const int* __restrict__ cnt, const int* __restrict__ colidx,
                                const float* __restrict__ asrc, const float* __restrict__ adst,
                                const bf16* __restrict__ hgat, const bf16* __restrict__ hlin,
                                const float* __restrict__ b_gat, int relu,
                                bf16* __restrict__ out, int ldo, int n,
                                const float* __restrict__ ctrl,
                                const float* __restrict__ pert_table,
                                const int* __restrict__ pert) {
    int d = blockIdx.x * 8 + (threadIdx.x >> 5);
    int lane = threadIdx.x & 31;
    if (d >= n) return;
    float ad = adst[d];
    float e_self = leaky(asrc[d] + ad);
    int cn = cnt[d]; if (cn > CAP) cn = CAP;
    bool val0 = lane < cn;
    bool val1 = lane + 32 < cn;
    int sj0 = val0 ? colidx[d * CAP + lane] : d;
    int sj1 = val1 ? colidx[d * CAP + 32 + lane] : d;
    float ej0 = val0 ? leaky(asrc[sj0] + ad) : -1e30f;
    float ej1 = val1 ? leaky(asrc[sj1] + ad) : -1e30f;
    float mx = fmaxf(ej0, ej1);
    #pragma unroll
    for (int o = 16; o; o >>= 1) mx = fmaxf(mx, __shfl_xor(mx, o, 32));
    mx = fmaxf(mx, e_self);
    float wj0 = val0 ? __expf(ej0 - mx) : 0.0f;
    float wj1 = val1 ? __expf(ej1 - mx) : 0.0f;
    float ws = __expf(e_self - mx);
    float sm = wj0 + wj1;
    #pragma unroll
    for (int o = 16; o; o >>= 1) sm += __shfl_xor(sm, o, 32);
    float den = sm + ws;
    // hoist tail operands above the gather loop to overlap their latency
    bf16x4 hl = *reinterpret_cast<const bf16x4*>(hlin + (long long)d * 128 + 4 * lane);
    float4 bg = *reinterpret_cast<const float4*>(b_gat + 4 * lane);
    bf16x4 hd = *reinterpret_cast<const bf16x4*>(hgat + (long long)d * 128 + 4 * lane);
    float acc0 = ws * b2f(hd[0]), acc1 = ws * b2f(hd[1]);
    float acc2 = ws * b2f(hd[2]), acc3 = ws * b2f(hd[3]);
    int c1 = cn < 32 ? cn : 32;
    for (int j = 0; j < c1; j += 4) {  // masked full-width; pad slots add 0
        int s0 = __shfl(sj0, j, 32), s1 = __shfl(sj0, j + 1, 32);
        int s2 = __shfl(sj0, j + 2, 32), s3 = __shfl(sj0, j + 3, 32);
        float w0 = __shfl(wj0, j, 32), w1 = __shfl(wj0, j + 1, 32);
        float w2 = __shfl(wj0, j + 2, 32), w3 = __shfl(wj0, j + 3, 32);
        bf16x4 h0v = *reinterpret_cast<const bf16x4*>(hgat + (long long)s0 * 128 + 4 * lane);
        bf16x4 h1v = *reinterpret_cast<const bf16x4*>(hgat + (long long)s1 * 128 + 4 * lane);
        bf16x4 h2v = *reinterpret_cast<const bf16x4*>(hgat + (long long)s2 * 128 + 4 * lane);
        bf16x4 h3v = *reinterpret_cast<const bf16x4*>(hgat + (long long)s3 * 128 + 4 * lane);
        acc0 = fmaf(w0, b2f(h0v[0]), acc0); acc1 = fmaf(w0, b2f(h0v[1]), acc1);
        acc2 = fmaf(w0, b2f(h0v[2]), acc2); acc3 = fmaf(w0, b2f(h0v[3]), acc3);
        acc0 = fmaf(w1, b2f(h1v[0]), acc0); acc1 = fmaf(w1, b2f(h1v[1]), acc1);
        acc2 = fmaf(w1, b2f(h1v[2]), acc2); acc3 = fmaf(w1, b2f(h1v[3]), acc3);
        acc0 = fmaf(w2, b2f(h2v[0]), acc0); acc1 = fmaf(w2, b2f(h2v[1]), acc1);
        acc2 = fmaf(w2, b2f(h2v[2]), acc2); acc3 = fmaf(w2, b2f(h2v[3]), acc3);
        acc0 = fmaf(w3, b2f(h3v[0]), acc0); acc1 = fmaf(w3, b2f(h3v[1]), acc1);
        acc2 = fmaf(w3, b2f(h3v[2]), acc2); acc3 = fmaf(w3, b2f(h3v[3]), acc3);
    }
    for (int j = 32; j < cn; j += 4) {  // cold tail (deg>32), masked likewise
        int s0 = __shfl(sj1, j - 32, 32), s1 = __shfl(sj1, j - 31, 32);
        int s2 = __shfl(sj1, j - 30, 32), s3 = __shfl(sj1, j - 29, 32);
        float w0 = __shfl(wj1, j - 32, 32), w1 = __shfl(wj1, j - 31, 32);
        float w2 = __shfl(wj1, j - 30, 32), w3 = __shfl(wj1, j - 29, 32);
        bf16x4 h0v = *reinterpret_cast<const bf16x4*>(hgat + (long long)s0 * 128 + 4 * lane);
        bf16x4 h1v = *reinterpret_cast<const bf16x4*>(hgat + (long long)s1 * 128 + 4 * lane);
        bf16x4 h2v = *reinterpret_cast<const bf16x4*>(hgat + (long long)s2 * 128 + 4 * lane);
        bf16x4 h3v = *reinterpret_cast<const bf16x4*>(hgat + (long long)s3 * 128 + 4 * lane);
        acc0 = fmaf(w0, b2f(h0v[0]), acc0); acc1 = fmaf(w0, b2f(h0v[1]), acc1);
        acc2 = fmaf(w0, b2f(h0v[2]), acc2); acc3 = fmaf(w0, b2f(h0v[3]), acc3);
        acc0 = fmaf(w1, b2f(h1v[0]), acc0); acc1 = fmaf(w1, b2f(h1v[1]), acc1);
        acc2 = fmaf(w1, b2f(h1v[2]), acc2); acc3 = fmaf(w1, b2f(h1v[3]), acc3);
        acc0 = fmaf(w2, b2f(h2v[0]), acc0); acc1 = fmaf(w2, b2f(h2v[1]), acc1);
        acc2 = fmaf(w2, b2f(h2v[2]), acc2); acc3 = fmaf(w2, b2f(h2v[3]), acc3);
        acc0 = fmaf(w3, b2f(h3v[0]), acc0); acc1 = fmaf(w3, b2f(h3v[1]), acc1);
        acc2 = fmaf(w3, b2f(h3v[2]), acc2); acc3 = fmaf(w3, b2f(h3v[3]), acc3);
    }
    float inv = 1.0f / den;
    float o0 = acc0 * inv + bg.x + b2f(hl[0]);
    float o1 = acc1 * inv + bg.y + b2f(hl[1]);
    float o2 = acc2 * inv + bg.z + b2f(hl[2]);
    float o3 = acc3 * inv + bg.w + b2f(hl[3]);
    if (relu) {
        o0 = fmaxf(o0, 0.0f); o1 = fmaxf(o1, 0.0f);
        o2 = fmaxf(o2, 0.0f); o3 = fmaxf(o3, 0.0f);
    }
    bf16* orow = out + (long long)d * ldo;
    bf16x4 ov; ov[0] = f2b(o0); ov[1] = f2b(o1); ov[2] = f2b(o2); ov[3] = f2b(o3);
    *reinterpret_cast<bf16x4*>(orow + 4 * lane) = ov;
    if (pert) {
        const float* p = pert_table + (long long)pert[d] * 128;
        if (lane == 0) orow[128] = f2b(ctrl[d]);
        orow[129 + lane] = f2b(p[lane]);
        orow[161 + lane] = f2b(p[32 + lane]);
        orow[193 + lane] = f2b(p[64 + lane]);
        orow[225 + lane] = f2b(p[96 + lane]);
        if (lane < 31) orow[257 + lane] = (bf16)0.0f;
    }
}

// ---------------------------------------------------------------------------
extern "C" void kernel_launch(void* const* d_in, const int* in_sizes, int n_in,
                              void* d_out, int out_size, void* d_ws, size_t ws_size,
                              hipStream_t stream) {
    const int N = in_sizes[0] / 64;   // 100000
    const int E = in_sizes[1] / 2;    // 1000000

    const float* x          = (const float*)d_in[0];
    const int*   ei         = (const int*)d_in[1];
    const int*   e_src      = ei;
    const int*   e_dst      = ei + E;
    const int*   pert       = (const int*)d_in[3];
    const float* ctrl       = (const float*)d_in[4];
    const int*   pos        = (const int*)d_in[5];
    const float* gene_table = (const float*)d_in[6];
    const float* pert_table = (const float*)d_in[7];
    const float* W1   = (const float*)d_in[8];
    const float* a_s1 = (const float*)d_in[9];
    const float* a_d1 = (const float*)d_in[10];
    const float* b1   = (const float*)d_in[11];
    const float* Wl1  = (const float*)d_in[12];
    const float* bl1  = (const float*)d_in[13];
    const float* W2   = (const float*)d_in[14];
    const float* a_s2 = (const float*)d_in[15];
    const float* a_d2 = (const float*)d_in[16];
    const float* b2   = (const float*)d_in[17];
    const float* Wl2  = (const float*)d_in[18];
    const float* bl2  = (const float*)d_in[19];
    const float* Wm1  = (const float*)d_in[20];
    const float* bm1  = (const float*)d_in[21];
    const float* Wm2  = (const float*)d_in[22];
    const float* bm2  = (const float*)d_in[23];

    // workspace layout (zbuf region kept even though h0 is no longer written)
    char* ws = (char*)d_ws;
    size_t off = 0;
    auto alloc = [&](size_t bytes) {
        char* p = ws + off;
        off = (off + bytes + 255) & ~(size_t)255;
        return p;
    };
    bf16* hgat   = (bf16*)alloc((size_t)N * 128 * 2);
    bf16* hlin   = (bf16*)alloc((size_t)N * 128 * 2);
    bf16* zregion= (bf16*)alloc((size_t)N * 192 * 2);    // z (N x 288) backing (spans next alloc too)
    bf16* h1     = (bf16*)alloc((size_t)N * 128 * 2);
    bf16* zbuf   = zregion;                              // z rows overlay zregion+h1 (h1 dead by then)
    float* asrc  = (float*)alloc((size_t)N * 4);
    float* adst  = (float*)alloc((size_t)N * 4);
    int* cnt     = (int*)alloc((size_t)N * 4);
    int* colidx  = (int*)alloc((size_t)N * CAP * 4);     // padded CSR
    bf16* w1s    = (bf16*)alloc((size_t)3072 * 8 * 2);
    bf16* wl1s   = (bf16*)alloc((size_t)3072 * 8 * 2);
    bf16* w2s    = (bf16*)alloc((size_t)2048 * 8 * 2);
    bf16* wl2s   = (bf16*)alloc((size_t)2048 * 8 * 2);
    bf16* wm1s   = (bf16*)alloc((size_t)2304 * 8 * 2);
    (void)ws_size; (void)n_in; (void)out_size;

    float* out = (float*)d_out;

    const int NBSC = (E + 255) / 256;    // scatter blocks (1 edge/thr)
    const int NBG64 = (N + 63) / 64;     // column-split gemm grids
    const int NBG128 = (N + 127) / 128;  // mlp gemm grid
    dim3 blk(256);
    dim3 gridWave((N + 7) / 8);          // gat: 8 nodes/block (2 per wave)

    // --- cnt = 0 (needed by one-pass CSR scatter) ---
    hipMemsetAsync(cnt, 0, (size_t)N * 4, stream);
    // --- padded-CSR scatter + weight pre-swizzle (h0 build moved to gemm) ---
    hipLaunchKernelGGL(scatter_kernel, dim3(49 + NBSC), blk, 0, stream,
                       e_src, e_dst, cnt, colidx, E,
                       W1, Wl1, W2, Wl2, Wm1, w1s, wl1s, w2s, wl2s, wm1s);
    // --- layer 1 linear (fused h0 build in LDS + dual GEMM, col-split) ---
    hipLaunchKernelGGL((gemm_l1_kernel<6>), dim3(NBG64), blk, 0, stream,
                       x, gene_table, pos, w1s, wl1s, bl1, hgat, hlin, 128, N,
                       a_s1, a_d1, asrc, adst);
    // --- layer 1 aggregation -> h1 (with relu) ---
    hipLaunchKernelGGL(gat_edge_kernel, gridWave, blk, 0, stream,
                       cnt, colidx, asrc, adst, hgat, hlin, b1, 1, h1, 128, N,
                       (const float*)nullptr, (const float*)nullptr, (const int*)nullptr);
    // --- layer 2 linear (dual, col-split) ---
    hipLaunchKernelGGL((gemm_dual_kernel<4>), dim3(NBG64), blk, 0, stream,
                       h1, 128, w2s, wl2s, bl2, hgat, hlin, 128, N,
                       a_s2, a_d2, asrc, adst);
    // --- layer 2 aggregation -> z[:, 0:128] (stride 288, NO relu) + z-fill ---
    hipLaunchKernelGGL(gat_edge_kernel, gridWave, blk, 0, stream,
                       cnt, colidx, asrc, adst, hgat, hlin, b2, 0, zbuf, 288, N,
                       ctrl, pert_table, pert);
    // --- MLP (both layers fused into one gemm) ---
    hipLaunchKernelGGL((gemm_mlp_kernel<9, 4>), dim3(NBG128), blk, 0, stream,
                       zbuf, 288, wm1s, bm1, N, Wm2, bm2, out);
}

// Round 11
// 422.348 us; speedup vs baseline: 1.0137x; 1.0137x over previous
//
#include <hip/hip_runtime.h>
#include <hip/hip_bf16.h>

typedef __bf16 bf16;
typedef __bf16 bf16x8 __attribute__((ext_vector_type(8)));
typedef __bf16 bf16x4 __attribute__((ext_vector_type(4)));
typedef __bf16 bf16x2 __attribute__((ext_vector_type(2)));
typedef float f32x4 __attribute__((ext_vector_type(4)));

#define CAP 48  // padded-CSR capacity; deg ~ Poisson(10), P(deg>=48) ~ 1e-18/node

__device__ __forceinline__ float b2f(bf16 v) { return (float)v; }
__device__ __forceinline__ bf16 f2b(float v) { return (bf16)v; }

__device__ __forceinline__ float leaky(float x) { return fmaxf(x, 0.2f * x); }

__device__ __forceinline__ bf16x8 zero8() {
    bf16x8 v;
    #pragma unroll
    for (int j = 0; j < 8; ++j) v[j] = (bf16)0.0f;
    return v;
}

// ---------------- weight pre-swizzle into MFMA fragment layout (bf16) ------
// frag f=(kb,nt,ln): dst[f*8+j] = W[kb*32 + (ln>>4)*8 + j][nt*16 + (ln&15)]
__device__ __forceinline__ void swizzle_one(const float* __restrict__ W, bf16* __restrict__ dst,
                                            int f, int NT, int Kreal, int C) {
    int kb = f / (NT * 64);
    int rem = f % (NT * 64);
    int nt = rem / 64;
    int ln = rem % 64;
    int q = ln >> 4, m = ln & 15;
    int c = nt * 16 + m;
    bf16x8 v;
    #pragma unroll
    for (int j = 0; j < 8; ++j) {
        int k = kb * 32 + q * 8 + j;
        v[j] = (k < Kreal) ? f2b(W[k * C + c]) : (bf16)0.0f;
    }
    *reinterpret_cast<bf16x8*>(dst + f * 8) = v;
}

// ---------------- fused prep: scatter (1:4 interleaved) + swizzle + rnorm --
// Role by blockIdx%5: r==0 -> padded-CSR scatter (1 edge/thread, NT store);
// r!=0 -> first 49 blocks weight swizzle, rest per-TABLE-row max-norm scale
// gscale[t] (gene_table read coalesced ONCE, 10MB, vs 51MB gathered before).
// h0 is never materialized: layer-1 GEMM builds A-fragments from x/gene
// directly in registers (no LDS latency phase — round-7 lesson).
__global__ void prep_kernel(const float* __restrict__ gene_table, int tg,
                            const float* __restrict__ W1, const float* __restrict__ Wl1,
                            const float* __restrict__ W2, const float* __restrict__ Wl2,
                            const float* __restrict__ Wm1,
                            bf16* __restrict__ w1s, bf16* __restrict__ wl1s,
                            bf16* __restrict__ w2s, bf16* __restrict__ wl2s,
                            bf16* __restrict__ wm1s, float* __restrict__ gscale,
                            const int* __restrict__ e_src, const int* __restrict__ e_dst,
                            int* __restrict__ cnt, int* __restrict__ colidx,
                            int e, int nbsc, int nboth) {
    int g5 = blockIdx.x / 5, r5 = blockIdx.x % 5;
    if (r5 == 0) {
        if (g5 >= nbsc) return;
        int i = g5 * blockDim.x + threadIdx.x;
        if (i < e) {
            int d = __builtin_nontemporal_load(e_dst + i);
            int s = __builtin_nontemporal_load(e_src + i);
            int k = atomicAdd(&cnt[d], 1);
            if (k < CAP) __builtin_nontemporal_store(s, colidx + d * CAP + k);
        }
        return;
    }
    int ob = g5 * 4 + (r5 - 1);
    if (ob >= nboth) return;
    if (ob < 49) {
        int g = ob * blockDim.x + threadIdx.x;
        if (g < 3072)        swizzle_one(W1,  w1s,  g,          8, 192, 128);
        else if (g < 6144)   swizzle_one(Wl1, wl1s, g - 3072,   8, 192, 128);
        else if (g < 8192)   swizzle_one(W2,  w2s,  g - 6144,   8, 128, 128);
        else if (g < 10240)  swizzle_one(Wl2, wl2s, g - 8192,   8, 128, 128);
        else if (g < 12544)  swizzle_one(Wm1, wm1s, g - 10240,  4, 257,  64);
        return;
    }
    int t = (ob - 49) * 8 + (threadIdx.x >> 5);  // table row
    int l = threadIdx.x & 31;
    if (t >= tg) return;
    const float* g = gene_table + (long long)t * 128;
    float4 p = reinterpret_cast<const float4*>(g)[l];
    float ss = p.x * p.x + p.y * p.y + p.z * p.z + p.w * p.w;
    #pragma unroll
    for (int o = 16; o; o >>= 1) ss += __shfl_xor(ss, o);
    float nrm = sqrtf(ss);
    float sc = nrm > 1.0f ? 1.0f / (nrm + 1e-7f) : 1.0f;
    if (l == 0) gscale[t] = sc;
}

// ---------------- layer-1 A-fragment: built in registers at load time ------
// cols 0..63 = f2b(x), cols 64..191 = f2b(gene * sc). Same roundings as the
// old h0 materialization -> bit-identical. kb is compile-time (unrolled).
__device__ __forceinline__ bf16x8 l1_frag(const float* __restrict__ xr,
                                          const float* __restrict__ gr,
                                          float sc, int kb, int q, bool valid) {
    if (!valid) return zero8();
    bf16x8 v;
    if (kb < 2) {
        int k0 = kb * 32 + q * 8;
        float4 a = *reinterpret_cast<const float4*>(xr + k0);
        float4 b = *reinterpret_cast<const float4*>(xr + k0 + 4);
        v[0] = f2b(a.x); v[1] = f2b(a.y); v[2] = f2b(a.z); v[3] = f2b(a.w);
        v[4] = f2b(b.x); v[5] = f2b(b.y); v[6] = f2b(b.z); v[7] = f2b(b.w);
    } else {
        int k0 = kb * 32 + q * 8 - 64;
        float4 a = *reinterpret_cast<const float4*>(gr + k0);
        float4 b = *reinterpret_cast<const float4*>(gr + k0 + 4);
        v[0] = f2b(a.x * sc); v[1] = f2b(a.y * sc); v[2] = f2b(a.z * sc); v[3] = f2b(a.w * sc);
        v[4] = f2b(b.x * sc); v[5] = f2b(b.y * sc); v[6] = f2b(b.z * sc); v[7] = f2b(b.w * sc);
    }
    return v;
}

// ---------------- layer-1 dual GEMM, direct x/gene A-loads -----------------
// Same proven per-lane-load skeleton as gemm_dual (no LDS A, no extra
// barrier); only the A addressing differs.
template <int KB>
__global__ __launch_bounds__(256) void gemm_l1_kernel(
    const float* __restrict__ x,
    const float* __restrict__ gene_table,
    const int* __restrict__ pos,
    const float* __restrict__ gscale,
    const bf16* __restrict__ Wg, const bf16* __restrict__ Wl,
    const float* __restrict__ bias_l,
    bf16* __restrict__ outg, bf16* __restrict__ outl, int ldo, int nrows,
    const float* __restrict__ attn_s, const float* __restrict__ attn_d,
    float* __restrict__ asrc, float* __restrict__ adst) {
    const int NTT = 8;  // total col tiles
    __shared__ float sA[64][2];
    int tid = threadIdx.x;
    int wave = tid >> 6, lane = tid & 63;
    int q = lane >> 4, m = lane & 15;
    int nt0 = (wave & 1) * 4;
    long long row_base = (long long)blockIdx.x * 64 + (wave >> 1) * 32;
    long long r0 = row_base + m;
    long long r1 = row_base + 16 + m;
    bool v0 = r0 < nrows, v1 = r1 < nrows;

    // per-row source pointers + norm scale (pos/gscale loads overlap kb=0 x-loads)
    const float* xr0 = x + r0 * 64;
    const float* xr1 = x + r1 * 64;
    int pt0 = v0 ? pos[r0] : 0;
    int pt1 = v1 ? pos[r1] : 0;
    const float* gr0 = gene_table + (long long)pt0 * 128;
    const float* gr1 = gene_table + (long long)pt1 * 128;
    float sc0 = v0 ? gscale[pt0] : 0.0f;
    float sc1 = v1 ? gscale[pt1] : 0.0f;

    f32x4 accg[2][4], accl[2][4];
    #pragma unroll
    for (int t = 0; t < 2; ++t)
        #pragma unroll
        for (int nt = 0; nt < 4; ++nt) {
            f32x4 z = {0.f, 0.f, 0.f, 0.f};
            accg[t][nt] = z; accl[t][nt] = z;
        }

    bf16x8 b0 = l1_frag(xr0, gr0, sc0, 0, q, v0);
    bf16x8 b1 = l1_frag(xr1, gr1, sc1, 0, q, v1);
    #pragma unroll
    for (int kb = 0; kb < KB; ++kb) {
        bf16x8 nb0, nb1;
        if (kb + 1 < KB) {
            nb0 = l1_frag(xr0, gr0, sc0, kb + 1, q, v0);
            nb1 = l1_frag(xr1, gr1, sc1, kb + 1, q, v1);
        }
        #pragma unroll
        for (int nt = 0; nt < 4; ++nt) {
            bf16x8 wg = *reinterpret_cast<const bf16x8*>(Wg + ((kb * NTT + nt0 + nt) * 64 + lane) * 8);
            bf16x8 wl = *reinterpret_cast<const bf16x8*>(Wl + ((kb * NTT + nt0 + nt) * 64 + lane) * 8);
            accg[0][nt] = __builtin_amdgcn_mfma_f32_16x16x32_bf16(wg, b0, accg[0][nt], 0, 0, 0);
            accg[1][nt] = __builtin_amdgcn_mfma_f32_16x16x32_bf16(wg, b1, accg[1][nt], 0, 0, 0);
            accl[0][nt] = __builtin_amdgcn_mfma_f32_16x16x32_bf16(wl, b0, accl[0][nt], 0, 0, 0);
            accl[1][nt] = __builtin_amdgcn_mfma_f32_16x16x32_bf16(wl, b1, accl[1][nt], 0, 0, 0);
        }
        b0 = nb0; b1 = nb1;
    }
    #pragma unroll
    for (int t = 0; t < 2; ++t) {
        long long row = t ? r1 : r0;
        if (row < nrows) {
            #pragma unroll
            for (int nt = 0; nt < 4; ++nt) {
                int c0 = (nt0 + nt) * 16 + q * 4;
                bf16x4 og, ol;
                #pragma unroll
                for (int r = 0; r < 4; ++r) {
                    og[r] = f2b(accg[t][nt][r]);
                    ol[r] = f2b(accl[t][nt][r] + bias_l[c0 + r]);
                }
                *reinterpret_cast<bf16x4*>(outg + row * ldo + c0) = og;
                *reinterpret_cast<bf16x4*>(outl + row * ldo + c0) = ol;
            }
        }
    }
    float svt[2], dvt[2];
    #pragma unroll
    for (int t = 0; t < 2; ++t) {
        float sv = 0.f, dv = 0.f;
        #pragma unroll
        for (int nt = 0; nt < 4; ++nt) {
            int c0 = (nt0 + nt) * 16 + q * 4;
            #pragma unroll
            for (int r = 0; r < 4; ++r) {
                float v = accg[t][nt][r];
                sv = fmaf(v, attn_s[c0 + r], sv);
                dv = fmaf(v, attn_d[c0 + r], dv);
            }
        }
        sv += __shfl_xor(sv, 16); sv += __shfl_xor(sv, 32);
        dv += __shfl_xor(dv, 16); dv += __shfl_xor(dv, 32);
        svt[t] = sv; dvt[t] = dv;
        if ((wave & 1) == 0 && q == 0) {
            int rloc = (wave >> 1) * 32 + t * 16 + m;
            sA[rloc][0] = sv; sA[rloc][1] = dv;
        }
    }
    __syncthreads();
    #pragma unroll
    for (int t = 0; t < 2; ++t) {
        long long row = t ? r1 : r0;
        if ((wave & 1) == 1 && q == 0 && row < nrows) {
            int rloc = (wave >> 1) * 32 + t * 16 + m;
            asrc[row] = svt[t] + sA[rloc][0];
            adst[row] = dvt[t] + sA[rloc][1];
        }
    }
}

// ---------------- dual GEMM (layer 2), column-split across waves -----------
template <int KB>
__global__ __launch_bounds__(256) void gemm_dual_kernel(
    const bf16* __restrict__ A, int lda,
    const bf16* __restrict__ Wg, const bf16* __restrict__ Wl,
    const float* __restrict__ bias_l,
    bf16* __restrict__ outg, bf16* __restrict__ outl, int ldo, int nrows,
    const float* __restrict__ attn_s, const float* __restrict__ attn_d,
    float* __restrict__ asrc, float* __restrict__ adst) {
    const int NTT = 8;  // total col tiles
    __shared__ float sA[64][2];
    int tid = threadIdx.x;
    int wave = tid >> 6, lane = tid & 63;
    int q = lane >> 4, m = lane & 15;
    int nt0 = (wave & 1) * 4;
    long long row_base = (long long)blockIdx.x * 64 + (wave >> 1) * 32;
    long long r0 = row_base + m;
    long long r1 = row_base + 16 + m;
    bool v0 = r0 < nrows, v1 = r1 < nrows;

    f32x4 accg[2][4], accl[2][4];
    #pragma unroll
    for (int t = 0; t < 2; ++t)
        #pragma unroll
        for (int nt = 0; nt < 4; ++nt) {
            f32x4 z = {0.f, 0.f, 0.f, 0.f};
            accg[t][nt] = z; accl[t][nt] = z;
        }

    bf16x8 b0 = v0 ? *reinterpret_cast<const bf16x8*>(A + r0 * lda + q * 8) : zero8();
    bf16x8 b1 = v1 ? *reinterpret_cast<const bf16x8*>(A + r1 * lda + q * 8) : zero8();
    #pragma unroll
    for (int kb = 0; kb < KB; ++kb) {
        bf16x8 nb0, nb1;
        if (kb + 1 < KB) {
            nb0 = v0 ? *reinterpret_cast<const bf16x8*>(A + r0 * lda + (kb + 1) * 32 + q * 8) : zero8();
            nb1 = v1 ? *reinterpret_cast<const bf16x8*>(A + r1 * lda + (kb + 1) * 32 + q * 8) : zero8();
        }
        #pragma unroll
        for (int nt = 0; nt < 4; ++nt) {
            bf16x8 wg = *reinterpret_cast<const bf16x8*>(Wg + ((kb * NTT + nt0 + nt) * 64 + lane) * 8);
            bf16x8 wl = *reinterpret_cast<const bf16x8*>(Wl + ((kb * NTT + nt0 + nt) * 64 + lane) * 8);
            accg[0][nt] = __builtin_amdgcn_mfma_f32_16x16x32_bf16(wg, b0, accg[0][nt], 0, 0, 0);
            accg[1][nt] = __builtin_amdgcn_mfma_f32_16x16x32_bf16(wg, b1, accg[1][nt], 0, 0, 0);
            accl[0][nt] = __builtin_amdgcn_mfma_f32_16x16x32_bf16(wl, b0, accl[0][nt], 0, 0, 0);
            accl[1][nt] = __builtin_amdgcn_mfma_f32_16x16x32_bf16(wl, b1, accl[1][nt], 0, 0, 0);
        }
        b0 = nb0; b1 = nb1;
    }
    #pragma unroll
    for (int t = 0; t < 2; ++t) {
        long long row = t ? r1 : r0;
        if (row < nrows) {
            #pragma unroll
            for (int nt = 0; nt < 4; ++nt) {
                int c0 = (nt0 + nt) * 16 + q * 4;
                bf16x4 og, ol;
                #pragma unroll
                for (int r = 0; r < 4; ++r) {
                    og[r] = f2b(accg[t][nt][r]);
                    ol[r] = f2b(accl[t][nt][r] + bias_l[c0 + r]);
                }
                *reinterpret_cast<bf16x4*>(outg + row * ldo + c0) = og;
                *reinterpret_cast<bf16x4*>(outl + row * ldo + c0) = ol;
            }
        }
    }
    float svt[2], dvt[2];
    #pragma unroll
    for (int t = 0; t < 2; ++t) {
        float sv = 0.f, dv = 0.f;
        #pragma unroll
        for (int nt = 0; nt < 4; ++nt) {
            int c0 = (nt0 + nt) * 16 + q * 4;
            #pragma unroll
            for (int r = 0; r < 4; ++r) {
                float v = accg[t][nt][r];
                sv = fmaf(v, attn_s[c0 + r], sv);
                dv = fmaf(v, attn_d[c0 + r], dv);
            }
        }
        sv += __shfl_xor(sv, 16); sv += __shfl_xor(sv, 32);
        dv += __shfl_xor(dv, 16); dv += __shfl_xor(dv, 32);
        svt[t] = sv; dvt[t] = dv;
        if ((wave & 1) == 0 && q == 0) {
            int rloc = (wave >> 1) * 32 + t * 16 + m;
            sA[rloc][0] = sv; sA[rloc][1] = dv;
        }
    }
    __syncthreads();
    #pragma unroll
    for (int t = 0; t < 2; ++t) {
        long long row = t ? r1 : r0;
        if ((wave & 1) == 1 && q == 0 && row < nrows) {
            int rloc = (wave >> 1) * 32 + t * 16 + m;
            asrc[row] = svt[t] + sA[rloc][0];
            adst[row] = dvt[t] + sA[rloc][1];
        }
    }
}

// ---------------- MLP GEMM: out = relu(relu(A@Wm1+bm1)@Wm2+bm2) ------------
template <int KB, int NT>
__global__ __launch_bounds__(256) void gemm_mlp_kernel(
    const bf16* __restrict__ A, int lda,
    const bf16* __restrict__ Wsw,
    const float* __restrict__ bias, int nrows,
    const float* __restrict__ Wm2, const float* __restrict__ bm2,
    float* __restrict__ out_final) {
    int tid = threadIdx.x;
    int wave = tid >> 6, lane = tid & 63;
    int q = lane >> 4, m = lane & 15;
    long long row_base = (long long)blockIdx.x * 128 + wave * 32;
    long long r0 = row_base + m;
    long long r1 = row_base + 16 + m;
    bool v0 = r0 < nrows, v1 = r1 < nrows;

    f32x4 acc[2][NT];
    #pragma unroll
    for (int t = 0; t < 2; ++t)
        #pragma unroll
        for (int nt = 0; nt < NT; ++nt) {
            f32x4 z = {0.f, 0.f, 0.f, 0.f};
            acc[t][nt] = z;
        }

    bf16x8 b0 = v0 ? *reinterpret_cast<const bf16x8*>(A + r0 * lda + q * 8) : zero8();
    bf16x8 b1 = v1 ? *reinterpret_cast<const bf16x8*>(A + r1 * lda + q * 8) : zero8();
    #pragma unroll
    for (int kb = 0; kb < KB; ++kb) {
        bf16x8 nb0, nb1;
        if (kb + 1 < KB) {
            nb0 = v0 ? *reinterpret_cast<const bf16x8*>(A + r0 * lda + (kb + 1) * 32 + q * 8) : zero8();
            nb1 = v1 ? *reinterpret_cast<const bf16x8*>(A + r1 * lda + (kb + 1) * 32 + q * 8) : zero8();
        }
        #pragma unroll
        for (int nt = 0; nt < NT; ++nt) {
            bf16x8 w = *reinterpret_cast<const bf16x8*>(Wsw + ((kb * NT + nt) * 64 + lane) * 8);
            acc[0][nt] = __builtin_amdgcn_mfma_f32_16x16x32_bf16(w, b0, acc[0][nt], 0, 0, 0);
            acc[1][nt] = __builtin_amdgcn_mfma_f32_16x16x32_bf16(w, b1, acc[1][nt], 0, 0, 0);
        }
        b0 = nb0; b1 = nb1;
    }
    #pragma unroll
    for (int t = 0; t < 2; ++t) {
        float sv = 0.f;
        #pragma unroll
        for (int nt = 0; nt < NT; ++nt) {
            int c0 = nt * 16 + q * 4;
            #pragma unroll
            for (int r = 0; r < 4; ++r) {
                float v = fmaxf(acc[t][nt][r] + bias[c0 + r], 0.0f);
                sv = fmaf(v, Wm2[c0 + r], sv);
            }
        }
        sv += __shfl_xor(sv, 16); sv += __shfl_xor(sv, 32);
        long long row = t ? r1 : r0;
        if (q == 0 && row < nrows) out_final[row] = fmaxf(sv + bm2[0], 0.0f);
    }
}

// ---------------- GAT aggregation: 2 nodes/wave, 32 lanes/node -------------
// Padded CSR (CAP slots/node, cnt[d] valid). Each 32-lane group owns one
// node; lane handles 4 channels (bf16x4 = 8 B loads). Invalid lanes carry
// wj=0 / sj=d, so FULL 4-wide iterations over padded slots are bit-exact:
// no serial remainder loop (for deg~10 the tail was ~half the iterations).
// Slot 1 (j = 32+lane) covers the statistically-cold 32 < deg <= CAP tail.
__global__ void gat_edge_kernel(const int* __restrict__ cnt, const int* __restrict__ colidx,
                                const float* __restrict__ asrc, const float* __restrict__ adst,
                                const bf16* __restrict__ hgat, const bf16* __restrict__ hlin,
                                const float* __restrict__ b_gat, int relu,
                                bf16* __restrict__ out, int ldo, int n,
                                const float* __restrict__ ctrl,
                                const float* __restrict__ pert_table,
                                const int* __restrict__ pert) {
    int d = blockIdx.x * 8 + (threadIdx.x >> 5);
    int lane = threadIdx.x & 31;
    if (d >= n) return;
    float ad = adst[d];
    float e_self = leaky(asrc[d] + ad);
    int cn = cnt[d]; if (cn > CAP) cn = CAP;
    bool val0 = lane < cn;
    bool val1 = lane + 32 < cn;
    int sj0 = val0 ? colidx[d * CAP + lane] : d;
    int sj1 = val1 ? colidx[d * CAP + 32 + lane] : d;
    float ej0 = val0 ? leaky(asrc[sj0] + ad) : -1e30f;
    float ej1 = val1 ? leaky(asrc[sj1] + ad) : -1e30f;
    float mx = fmaxf(ej0, ej1);
    #pragma unroll
    for (int o = 16; o; o >>= 1) mx = fmaxf(mx, __shfl_xor(mx, o, 32));
    mx = fmaxf(mx, e_self);
    float wj0 = val0 ? __expf(ej0 - mx) : 0.0f;
    float wj1 = val1 ? __expf(ej1 - mx) : 0.0f;
    float ws = __expf(e_self - mx);
    float sm = wj0 + wj1;
    #pragma unroll
    for (int o = 16; o; o >>= 1) sm += __shfl_xor(sm, o, 32);
    float den = sm + ws;
    // hoist tail operands above the gather loop to overlap their latency
    bf16x4 hl = *reinterpret_cast<const bf16x4*>(hlin + (long long)d * 128 + 4 * lane);
    float4 bg = *reinterpret_cast<const float4*>(b_gat + 4 * lane);
    bf16x4 hd = *reinterpret_cast<const bf16x4*>(hgat + (long long)d * 128 + 4 * lane);
    float acc0 = ws * b2f(hd[0]), acc1 = ws * b2f(hd[1]);
    float acc2 = ws * b2f(hd[2]), acc3 = ws * b2f(hd[3]);
    int c1 = cn < 32 ? cn : 32;
    for (int j = 0; j < c1; j += 4) {  // masked full-width; pad slots add 0
        int s0 = __shfl(sj0, j, 32), s1 = __shfl(sj0, j + 1, 32);
        int s2 = __shfl(sj0, j + 2, 32), s3 = __shfl(sj0, j + 3, 32);
        float w0 = __shfl(wj0, j, 32), w1 = __shfl(wj0, j + 1, 32);
        float w2 = __shfl(wj0, j + 2, 32), w3 = __shfl(wj0, j + 3, 32);
        bf16x4 h0v = *reinterpret_cast<const bf16x4*>(hgat + (long long)s0 * 128 + 4 * lane);
        bf16x4 h1v = *reinterpret_cast<const bf16x4*>(hgat + (long long)s1 * 128 + 4 * lane);
        bf16x4 h2v = *reinterpret_cast<const bf16x4*>(hgat + (long long)s2 * 128 + 4 * lane);
        bf16x4 h3v = *reinterpret_cast<const bf16x4*>(hgat + (long long)s3 * 128 + 4 * lane);
        acc0 = fmaf(w0, b2f(h0v[0]), acc0); acc1 = fmaf(w0, b2f(h0v[1]), acc1);
        acc2 = fmaf(w0, b2f(h0v[2]), acc2); acc3 = fmaf(w0, b2f(h0v[3]), acc3);
        acc0 = fmaf(w1, b2f(h1v[0]), acc0); acc1 = fmaf(w1, b2f(h1v[1]), acc1);
        acc2 = fmaf(w1, b2f(h1v[2]), acc2); acc3 = fmaf(w1, b2f(h1v[3]), acc3);
        acc0 = fmaf(w2, b2f(h2v[0]), acc0); acc1 = fmaf(w2, b2f(h2v[1]), acc1);
        acc2 = fmaf(w2, b2f(h2v[2]), acc2); acc3 = fmaf(w2, b2f(h2v[3]), acc3);
        acc0 = fmaf(w3, b2f(h3v[0]), acc0); acc1 = fmaf(w3, b2f(h3v[1]), acc1);
        acc2 = fmaf(w3, b2f(h3v[2]), acc2); acc3 = fmaf(w3, b2f(h3v[3]), acc3);
    }
    for (int j = 32; j < cn; j += 4) {  // cold tail (deg>32), masked likewise
        int s0 = __shfl(sj1, j - 32, 32), s1 = __shfl(sj1, j - 31, 32);
        int s2 = __shfl(sj1, j - 30, 32), s3 = __shfl(sj1, j - 29, 32);
        float w0 = __shfl(wj1, j - 32, 32), w1 = __shfl(wj1, j - 31, 32);
        float w2 = __shfl(wj1, j - 30, 32), w3 = __shfl(wj1, j - 29, 32);
        bf16x4 h0v = *reinterpret_cast<const bf16x4*>(hgat + (long long)s0 * 128 + 4 * lane);
        bf16x4 h1v = *reinterpret_cast<const bf16x4*>(hgat + (long long)s1 * 128 + 4 * lane);
        bf16x4 h2v = *reinterpret_cast<const bf16x4*>(hgat + (long long)s2 * 128 + 4 * lane);
        bf16x4 h3v = *reinterpret_cast<const bf16x4*>(hgat + (long long)s3 * 128 + 4 * lane);
        acc0 = fmaf(w0, b2f(h0v[0]), acc0); acc1 = fmaf(w0, b2f(h0v[1]), acc1);
        acc2 = fmaf(w0, b2f(h0v[2]), acc2); acc3 = fmaf(w0, b2f(h0v[3]), acc3);
        acc0 = fmaf(w1, b2f(h1v[0]), acc0); acc1 = fmaf(w1, b2f(h1v[1]), acc1);
        acc2 = fmaf(w1, b2f(h1v[2]), acc2); acc3 = fmaf(w1, b2f(h1v[3]), acc3);
        acc0 = fmaf(w2, b2f(h2v[0]), acc0); acc1 = fmaf(w2, b2f(h2v[1]), acc1);
        acc2 = fmaf(w2, b2f(h2v[2]), acc2); acc3 = fmaf(w2, b2f(h2v[3]), acc3);
        acc0 = fmaf(w3, b2f(h3v[0]), acc0); acc1 = fmaf(w3, b2f(h3v[1]), acc1);
        acc2 = fmaf(w3, b2f(h3v[2]), acc2); acc3 = fmaf(w3, b2f(h3v[3]), acc3);
    }
    float inv = 1.0f / den;
    float o0 = acc0 * inv + bg.x + b2f(hl[0]);
    float o1 = acc1 * inv + bg.y + b2f(hl[1]);
    float o2 = acc2 * inv + bg.z + b2f(hl[2]);
    float o3 = acc3 * inv + bg.w + b2f(hl[3]);
    if (relu) {
        o0 = fmaxf(o0, 0.0f); o1 = fmaxf(o1, 0.0f);
        o2 = fmaxf(o2, 0.0f); o3 = fmaxf(o3, 0.0f);
    }
    bf16* orow = out + (long long)d * ldo;
    bf16x4 ov; ov[0] = f2b(o0); ov[1] = f2b(o1); ov[2] = f2b(o2); ov[3] = f2b(o3);
    *reinterpret_cast<bf16x4*>(orow + 4 * lane) = ov;
    if (pert) {
        const float* p = pert_table + (long long)pert[d] * 128;
        if (lane == 0) orow[128] = f2b(ctrl[d]);
        orow[129 + lane] = f2b(p[lane]);
        orow[161 + lane] = f2b(p[32 + lane]);
        orow[193 + lane] = f2b(p[64 + lane]);
        orow[225 + lane] = f2b(p[96 + lane]);
        if (lane < 31) orow[257 + lane] = (bf16)0.0f;
    }
}

// ---------------------------------------------------------------------------
extern "C" void kernel_launch(void* const* d_in, const int* in_sizes, int n_in,
                              void* d_out, int out_size, void* d_ws, size_t ws_size,
                              hipStream_t stream) {
    const int N = in_sizes[0] / 64;    // 100000
    const int E = in_sizes[1] / 2;     // 1000000
    const int TG = in_sizes[6] / 128;  // 20000 gene-table rows

    const float* x          = (const float*)d_in[0];
    const int*   ei         = (const int*)d_in[1];
    const int*   e_src      = ei;
    const int*   e_dst      = ei + E;
    const int*   pert       = (const int*)d_in[3];
    const float* ctrl       = (const float*)d_in[4];
    const int*   pos        = (const int*)d_in[5];
    const float* gene_table = (const float*)d_in[6];
    const float* pert_table = (const float*)d_in[7];
    const float* W1   = (const float*)d_in[8];
    const float* a_s1 = (const float*)d_in[9];
    const float* a_d1 = (const float*)d_in[10];
    const float* b1   = (const float*)d_in[11];
    const float* Wl1  = (const float*)d_in[12];
    const float* bl1  = (const float*)d_in[13];
    const float* W2   = (const float*)d_in[14];
    const float* a_s2 = (const float*)d_in[15];
    const float* a_d2 = (const float*)d_in[16];
    const float* b2   = (const float*)d_in[17];
    const float* Wl2  = (const float*)d_in[18];
    const float* bl2  = (const float*)d_in[19];
    const float* Wm1  = (const float*)d_in[20];
    const float* bm1  = (const float*)d_in[21];
    const float* Wm2  = (const float*)d_in[22];
    const float* bm2  = (const float*)d_in[23];

    // workspace layout (round-7-verified overlay: z spans zregion+h1)
    char* ws = (char*)d_ws;
    size_t off = 0;
    auto alloc = [&](size_t bytes) {
        char* p = ws + off;
        off = (off + bytes + 255) & ~(size_t)255;
        return p;
    };
    bf16* hgat   = (bf16*)alloc((size_t)N * 128 * 2);
    bf16* hlin   = (bf16*)alloc((size_t)N * 128 * 2);
    bf16* zregion= (bf16*)alloc((size_t)N * 192 * 2);    // z (N x 288) backing (spans next alloc too)
    bf16* h1     = (bf16*)alloc((size_t)N * 128 * 2);
    bf16* zbuf   = zregion;                              // z rows overlay zregion+h1 (h1 dead by then)
    float* asrc  = (float*)alloc((size_t)N * 4);
    float* adst  = (float*)alloc((size_t)N * 4);
    int* cnt     = (int*)alloc((size_t)N * 4);
    int* colidx  = (int*)alloc((size_t)N * CAP * 4);     // padded CSR
    bf16* w1s    = (bf16*)alloc((size_t)3072 * 8 * 2);
    bf16* wl1s   = (bf16*)alloc((size_t)3072 * 8 * 2);
    bf16* w2s    = (bf16*)alloc((size_t)2048 * 8 * 2);
    bf16* wl2s   = (bf16*)alloc((size_t)2048 * 8 * 2);
    bf16* wm1s   = (bf16*)alloc((size_t)2304 * 8 * 2);
    float* gscale= (float*)alloc((size_t)TG * 4);        // per-table-row max-norm scale
    (void)ws_size; (void)n_in; (void)out_size;

    float* out = (float*)d_out;

    const int NBSC = (E + 255) / 256;        // scatter blocks (1 edge/thr)
    const int NBOTH = 49 + (TG + 7) / 8;     // swizzle + rnorm blocks
    const int NG5 = (NBSC > (NBOTH + 3) / 4) ? NBSC : (NBOTH + 3) / 4;
    const int NBPREP = NG5 * 5;              // 1:4 interleave (scatter : other)
    const int NBG64 = (N + 63) / 64;         // column-split gemm grids
    const int NBG128 = (N + 127) / 128;      // mlp gemm grid
    dim3 blk(256);
    dim3 gridWave((N + 7) / 8);              // gat: 8 nodes/block (2 per wave)

    // --- cnt = 0 (needed by one-pass CSR scatter) ---
    hipMemsetAsync(cnt, 0, (size_t)N * 4, stream);
    // --- padded-CSR scatter (interleaved 1:4) + weight swizzle + rnorm ---
    hipLaunchKernelGGL(prep_kernel, dim3(NBPREP), blk, 0, stream,
                       gene_table, TG, W1, Wl1, W2, Wl2, Wm1,
                       w1s, wl1s, w2s, wl2s, wm1s, gscale,
                       e_src, e_dst, cnt, colidx, E, NBSC, NBOTH);
    // --- layer 1 linear (direct x/gene A-loads, dual, col-split) ---
    hipLaunchKernelGGL((gemm_l1_kernel<6>), dim3(NBG64), blk, 0, stream,
                       x, gene_table, pos, gscale, w1s, wl1s, bl1, hgat, hlin, 128, N,
                       a_s1, a_d1, asrc, adst);
    // --- layer 1 aggregation -> h1 (with relu) ---
    hipLaunchKernelGGL(gat_edge_kernel, gridWave, blk, 0, stream,
                       cnt, colidx, asrc, adst, hgat, hlin, b1, 1, h1, 128, N,
                       (const float*)nullptr, (const float*)nullptr, (const int*)nullptr);
    // --- layer 2 linear (dual, col-split) ---
    hipLaunchKernelGGL((gemm_dual_kernel<4>), dim3(NBG64), blk, 0, stream,
                       h1, 128, w2s, wl2s, bl2, hgat, hlin, 128, N,
                       a_s2, a_d2, asrc, adst);
    // --- layer 2 aggregation -> z[:, 0:128] (stride 288, NO relu) + z-fill ---
    hipLaunchKernelGGL(gat_edge_kernel, gridWave, blk, 0, stream,
                       cnt, colidx, asrc, adst, hgat, hlin, b2, 0, zbuf, 288, N,
                       ctrl, pert_table, pert);
    // --- MLP (both layers fused into one gemm) ---
    hipLaunchKernelGGL((gemm_mlp_kernel<9, 4>), dim3(NBG128), blk, 0, stream,
                       zbuf, 288, wm1s, bm1, N, Wm2, bm2, out);
}

// Round 13
// 396.857 us; speedup vs baseline: 1.0788x; 1.0642x over previous
//
#include <hip/hip_runtime.h>
#include <hip/hip_bf16.h>

typedef __bf16 bf16;
typedef __bf16 bf16x8 __attribute__((ext_vector_type(8)));
typedef __bf16 bf16x4 __attribute__((ext_vector_type(4)));
typedef __bf16 bf16x2 __attribute__((ext_vector_type(2)));
typedef float f32x4 __attribute__((ext_vector_type(4)));

#define CAP 48  // padded-CSR capacity; deg ~ Poisson(10), P(deg>=48) ~ 1e-18/node

__device__ __forceinline__ float b2f(bf16 v) { return (float)v; }
__device__ __forceinline__ bf16 f2b(float v) { return (bf16)v; }

__device__ __forceinline__ float leaky(float x) { return fmaxf(x, 0.2f * x); }

__device__ __forceinline__ bf16x8 zero8() {
    bf16x8 v;
    #pragma unroll
    for (int j = 0; j < 8; ++j) v[j] = (bf16)0.0f;
    return v;
}

// ---------------- weight pre-swizzle into MFMA fragment layout (bf16) ------
// frag f=(kb,nt,ln): dst[f*8+j] = W[kb*32 + (ln>>4)*8 + j][nt*16 + (ln&15)]
__device__ __forceinline__ void swizzle_one(const float* __restrict__ W, bf16* __restrict__ dst,
                                            int f, int NT, int Kreal, int C) {
    int kb = f / (NT * 64);
    int rem = f % (NT * 64);
    int nt = rem / 64;
    int ln = rem % 64;
    int q = ln >> 4, m = ln & 15;
    int c = nt * 16 + m;
    bf16x8 v;
    #pragma unroll
    for (int j = 0; j < 8; ++j) {
        int k = kb * 32 + q * 8 + j;
        v[j] = (k < Kreal) ? f2b(W[k * C + c]) : (bf16)0.0f;
    }
    *reinterpret_cast<bf16x8*>(dst + f * 8) = v;
}

// ---------------- fused: padded-CSR scatter (4 edges/thr) + prep + h0 ------
// Role by blockIdx%5: r==0 -> scatter; r!=0 -> first 49 blocks weight
// swizzle, rest h0 build (8 nodes/block, 32 lanes/node).
// Scatter = 4 edges/thread (blockDim-strided, independent atomic chains):
// round-11 PMC showed pure-scatter at full concurrency is CONTENTION-bound
// (90us doing less work than this kernel's 65us) — fewer resident scatter
// waves + h0-role dilution is the governor that keeps atomic serialization
// and cross-XCD colidx line ping-pong low.
__global__ void h0_prep_kernel(const float* __restrict__ x,
                               const float* __restrict__ gene_table,
                               const int* __restrict__ pos,
                               bf16* __restrict__ h0, int n,
                               const float* __restrict__ W1, const float* __restrict__ Wl1,
                               const float* __restrict__ W2, const float* __restrict__ Wl2,
                               const float* __restrict__ Wm1,
                               bf16* __restrict__ w1s, bf16* __restrict__ wl1s,
                               bf16* __restrict__ w2s, bf16* __restrict__ wl2s,
                               bf16* __restrict__ wm1s,
                               const int* __restrict__ e_src, const int* __restrict__ e_dst,
                               int* __restrict__ cnt, int* __restrict__ colidx,
                               int e, int nbsc, int nboth) {
    int g5 = blockIdx.x / 5, r5 = blockIdx.x % 5;
    if (r5 == 0) {
        if (g5 >= nbsc) return;
        int base = g5 * (blockDim.x * 4) + threadIdx.x;
        #pragma unroll
        for (int u = 0; u < 4; ++u) {
            int i = base + u * blockDim.x;
            if (i < e) {
                int d = __builtin_nontemporal_load(e_dst + i);
                int s = __builtin_nontemporal_load(e_src + i);
                int k = atomicAdd(&cnt[d], 1);
                if (k < CAP) __builtin_nontemporal_store(s, colidx + d * CAP + k);
            }
        }
        return;
    }
    int ob = g5 * 4 + (r5 - 1);
    if (ob >= nboth) return;
    if (ob < 49) {
        int g = ob * blockDim.x + threadIdx.x;
        if (g < 3072)        swizzle_one(W1,  w1s,  g,          8, 192, 128);
        else if (g < 6144)   swizzle_one(Wl1, wl1s, g - 3072,   8, 192, 128);
        else if (g < 8192)   swizzle_one(W2,  w2s,  g - 6144,   8, 128, 128);
        else if (g < 10240)  swizzle_one(Wl2, wl2s, g - 8192,   8, 128, 128);
        else if (g < 12544)  swizzle_one(Wm1, wm1s, g - 10240,  4, 257,  64);
        return;
    }
    int wid = (ob - 49) * 8 + (threadIdx.x >> 5);
    int l = threadIdx.x & 31;
    if (wid >= n) return;
    const float* g = gene_table + (long long)pos[wid] * 128;
    float4 p = reinterpret_cast<const float4*>(g)[l];
    float ss = p.x * p.x + p.y * p.y + p.z * p.z + p.w * p.w;
    #pragma unroll
    for (int o = 16; o; o >>= 1) ss += __shfl_xor(ss, o);
    float nrm = sqrtf(ss);
    float sc = nrm > 1.0f ? 1.0f / (nrm + 1e-7f) : 1.0f;
    bf16* orow = h0 + (long long)wid * 192;
    float2 xv = reinterpret_cast<const float2*>(x + (long long)wid * 64)[l];
    bf16x2 xb; xb[0] = f2b(xv.x); xb[1] = f2b(xv.y);
    *reinterpret_cast<bf16x2*>(orow + 2 * l) = xb;
    bf16x4 gb;
    gb[0] = f2b(p.x * sc); gb[1] = f2b(p.y * sc);
    gb[2] = f2b(p.z * sc); gb[3] = f2b(p.w * sc);
    *reinterpret_cast<bf16x4*>(orow + 64 + 4 * l) = gb;
}

// ---------------- dual GEMM, column-split across waves ---------------------
// Block (256 thr) covers 64 rows x 128 cols. Wave = (row-half, col-half).
// Dual acc = 64 VGPR/wave. attn logits combined via LDS.
template <int KB>
__global__ __launch_bounds__(256) void gemm_dual_kernel(
    const bf16* __restrict__ A, int lda,
    const bf16* __restrict__ Wg, const bf16* __restrict__ Wl,
    const float* __restrict__ bias_l,
    bf16* __restrict__ outg, bf16* __restrict__ outl, int ldo, int nrows,
    const float* __restrict__ attn_s, const float* __restrict__ attn_d,
    float* __restrict__ asrc, float* __restrict__ adst) {
    const int NTT = 8;  // total col tiles
    __shared__ float sA[64][2];
    int tid = threadIdx.x;
    int wave = tid >> 6, lane = tid & 63;
    int q = lane >> 4, m = lane & 15;
    int nt0 = (wave & 1) * 4;
    long long row_base = (long long)blockIdx.x * 64 + (wave >> 1) * 32;
    long long r0 = row_base + m;
    long long r1 = row_base + 16 + m;
    bool v0 = r0 < nrows, v1 = r1 < nrows;

    f32x4 accg[2][4], accl[2][4];
    #pragma unroll
    for (int t = 0; t < 2; ++t)
        #pragma unroll
        for (int nt = 0; nt < 4; ++nt) {
            f32x4 z = {0.f, 0.f, 0.f, 0.f};
            accg[t][nt] = z; accl[t][nt] = z;
        }

    bf16x8 b0 = v0 ? *reinterpret_cast<const bf16x8*>(A + r0 * lda + q * 8) : zero8();
    bf16x8 b1 = v1 ? *reinterpret_cast<const bf16x8*>(A + r1 * lda + q * 8) : zero8();
    #pragma unroll
    for (int kb = 0; kb < KB; ++kb) {
        bf16x8 nb0, nb1;
        if (kb + 1 < KB) {
            nb0 = v0 ? *reinterpret_cast<const bf16x8*>(A + r0 * lda + (kb + 1) * 32 + q * 8) : zero8();
            nb1 = v1 ? *reinterpret_cast<const bf16x8*>(A + r1 * lda + (kb + 1) * 32 + q * 8) : zero8();
        }
        #pragma unroll
        for (int nt = 0; nt < 4; ++nt) {
            bf16x8 wg = *reinterpret_cast<const bf16x8*>(Wg + ((kb * NTT + nt0 + nt) * 64 + lane) * 8);
            bf16x8 wl = *reinterpret_cast<const bf16x8*>(Wl + ((kb * NTT + nt0 + nt) * 64 + lane) * 8);
            accg[0][nt] = __builtin_amdgcn_mfma_f32_16x16x32_bf16(wg, b0, accg[0][nt], 0, 0, 0);
            accg[1][nt] = __builtin_amdgcn_mfma_f32_16x16x32_bf16(wg, b1, accg[1][nt], 0, 0, 0);
            accl[0][nt] = __builtin_amdgcn_mfma_f32_16x16x32_bf16(wl, b0, accl[0][nt], 0, 0, 0);
            accl[1][nt] = __builtin_amdgcn_mfma_f32_16x16x32_bf16(wl, b1, accl[1][nt], 0, 0, 0);
        }
        b0 = nb0; b1 = nb1;
    }
    #pragma unroll
    for (int t = 0; t < 2; ++t) {
        long long row = t ? r1 : r0;
        if (row < nrows) {
            #pragma unroll
            for (int nt = 0; nt < 4; ++nt) {
                int c0 = (nt0 + nt) * 16 + q * 4;
                bf16x4 og, ol;
                #pragma unroll
                for (int r = 0; r < 4; ++r) {
                    og[r] = f2b(accg[t][nt][r]);
                    ol[r] = f2b(accl[t][nt][r] + bias_l[c0 + r]);
                }
                *reinterpret_cast<bf16x4*>(outg + row * ldo + c0) = og;
                *reinterpret_cast<bf16x4*>(outl + row * ldo + c0) = ol;
            }
        }
    }
    float svt[2], dvt[2];
    #pragma unroll
    for (int t = 0; t < 2; ++t) {
        float sv = 0.f, dv = 0.f;
        #pragma unroll
        for (int nt = 0; nt < 4; ++nt) {
            int c0 = (nt0 + nt) * 16 + q * 4;
            #pragma unroll
            for (int r = 0; r < 4; ++r) {
                float v = accg[t][nt][r];
                sv = fmaf(v, attn_s[c0 + r], sv);
                dv = fmaf(v, attn_d[c0 + r], dv);
            }
        }
        sv += __shfl_xor(sv, 16); sv += __shfl_xor(sv, 32);
        dv += __shfl_xor(dv, 16); dv += __shfl_xor(dv, 32);
        svt[t] = sv; dvt[t] = dv;
        if ((wave & 1) == 0 && q == 0) {
            int rloc = (wave >> 1) * 32 + t * 16 + m;
            sA[rloc][0] = sv; sA[rloc][1] = dv;
        }
    }
    __syncthreads();
    #pragma unroll
    for (int t = 0; t < 2; ++t) {
        long long row = t ? r1 : r0;
        if ((wave & 1) == 1 && q == 0 && row < nrows) {
            int rloc = (wave >> 1) * 32 + t * 16 + m;
            asrc[row] = svt[t] + sA[rloc][0];
            adst[row] = dvt[t] + sA[rloc][1];
        }
    }
}

// ---------------- MLP GEMM: out = relu(relu(A@Wm1+bm1)@Wm2+bm2) ------------
template <int KB, int NT>
__global__ __launch_bounds__(256) void gemm_mlp_kernel(
    const bf16* __restrict__ A, int lda,
    const bf16* __restrict__ Wsw,
    const float* __restrict__ bias, int nrows,
    const float* __restrict__ Wm2, const float* __restrict__ bm2,
    float* __restrict__ out_final) {
    int tid = threadIdx.x;
    int wave = tid >> 6, lane = tid & 63;
    int q = lane >> 4, m = lane & 15;
    long long row_base = (long long)blockIdx.x * 128 + wave * 32;
    long long r0 = row_base + m;
    long long r1 = row_base + 16 + m;
    bool v0 = r0 < nrows, v1 = r1 < nrows;

    f32x4 acc[2][NT];
    #pragma unroll
    for (int t = 0; t < 2; ++t)
        #pragma unroll
        for (int nt = 0; nt < NT; ++nt) {
            f32x4 z = {0.f, 0.f, 0.f, 0.f};
            acc[t][nt] = z;
        }

    bf16x8 b0 = v0 ? *reinterpret_cast<const bf16x8*>(A + r0 * lda + q * 8) : zero8();
    bf16x8 b1 = v1 ? *reinterpret_cast<const bf16x8*>(A + r1 * lda + q * 8) : zero8();
    #pragma unroll
    for (int kb = 0; kb < KB; ++kb) {
        bf16x8 nb0, nb1;
        if (kb + 1 < KB) {
            nb0 = v0 ? *reinterpret_cast<const bf16x8*>(A + r0 * lda + (kb + 1) * 32 + q * 8) : zero8();
            nb1 = v1 ? *reinterpret_cast<const bf16x8*>(A + r1 * lda + (kb + 1) * 32 + q * 8) : zero8();
        }
        #pragma unroll
        for (int nt = 0; nt < NT; ++nt) {
            bf16x8 w = *reinterpret_cast<const bf16x8*>(Wsw + ((kb * NT + nt) * 64 + lane) * 8);
            acc[0][nt] = __builtin_amdgcn_mfma_f32_16x16x32_bf16(w, b0, acc[0][nt], 0, 0, 0);
            acc[1][nt] = __builtin_amdgcn_mfma_f32_16x16x32_bf16(w, b1, acc[1][nt], 0, 0, 0);
        }
        b0 = nb0; b1 = nb1;
    }
    #pragma unroll
    for (int t = 0; t < 2; ++t) {
        float sv = 0.f;
        #pragma unroll
        for (int nt = 0; nt < NT; ++nt) {
            int c0 = nt * 16 + q * 4;
            #pragma unroll
            for (int r = 0; r < 4; ++r) {
                float v = fmaxf(acc[t][nt][r] + bias[c0 + r], 0.0f);
                sv = fmaf(v, Wm2[c0 + r], sv);
            }
        }
        sv += __shfl_xor(sv, 16); sv += __shfl_xor(sv, 32);
        long long row = t ? r1 : r0;
        if (q == 0 && row < nrows) out_final[row] = fmaxf(sv + bm2[0], 0.0f);
    }
}

// ---------------- GAT aggregation: 2 nodes/wave, 32 lanes/node -------------
// Padded CSR (CAP slots/node, cnt[d] valid). Each 32-lane group owns one
// node; lane handles 4 channels (bf16x4 = 8 B loads). Invalid lanes carry
// wj=0 / sj=d, so FULL 4-wide iterations over padded slots are bit-exact:
// no serial remainder loop (for deg~10 the tail was ~half the iterations).
// Slot 1 (j = 32+lane) covers the statistically-cold 32 < deg <= CAP tail.
__global__ void gat_edge_kernel(const int* __restrict__ cnt, const int* __restrict__ colidx,
                                const float* __restrict__ asrc, const float* __restrict__ adst,
                                const bf16* __restrict__ hgat, const bf16* __restrict__ hlin,
                                const float* __restrict__ b_gat, int relu,
                                bf16* __restrict__ out, int ldo, int n,
                                const float* __restrict__ ctrl,
                                const float* __restrict__ pert_table,
                                const int* __restrict__ pert) {
    int d = blockIdx.x * 8 + (threadIdx.x >> 5);
    int lane = threadIdx.x & 31;
    if (d >= n) return;
    float ad = adst[d];
    float e_self = leaky(asrc[d] + ad);
    int cn = cnt[d]; if (cn > CAP) cn = CAP;
    bool val0 = lane < cn;
    bool val1 = lane + 32 < cn;
    int sj0 = val0 ? colidx[d * CAP + lane] : d;
    int sj1 = val1 ? colidx[d * CAP + 32 + lane] : d;
    float ej0 = val0 ? leaky(asrc[sj0] + ad) : -1e30f;
    float ej1 = val1 ? leaky(asrc[sj1] + ad) : -1e30f;
    float mx = fmaxf(ej0, ej1);
    #pragma unroll
    for (int o = 16; o; o >>= 1) mx = fmaxf(mx, __shfl_xor(mx, o, 32));
    mx = fmaxf(mx, e_self);
    float wj0 = val0 ? __expf(ej0 - mx) : 0.0f;
    float wj1 = val1 ? __expf(ej1 - mx) : 0.0f;
    float ws = __expf(e_self - mx);
    float sm = wj0 + wj1;
    #pragma unroll
    for (int o = 16; o; o >>= 1) sm += __shfl_xor(sm, o, 32);
    float den = sm + ws;
    // hoist tail operands above the gather loop to overlap their latency
    bf16x4 hl = *reinterpret_cast<const bf16x4*>(hlin + (long long)d * 128 + 4 * lane);
    float4 bg = *reinterpret_cast<const float4*>(b_gat + 4 * lane);
    bf16x4 hd = *reinterpret_cast<const bf16x4*>(hgat + (long long)d * 128 + 4 * lane);
    float acc0 = ws * b2f(hd[0]), acc1 = ws * b2f(hd[1]);
    float acc2 = ws * b2f(hd[2]), acc3 = ws * b2f(hd[3]);
    int c1 = cn < 32 ? cn : 32;
    for (int j = 0; j < c1; j += 4) {  // masked full-width; pad slots add 0
        int s0 = __shfl(sj0, j, 32), s1 = __shfl(sj0, j + 1, 32);
        int s2 = __shfl(sj0, j + 2, 32), s3 = __shfl(sj0, j + 3, 32);
        float w0 = __shfl(wj0, j, 32), w1 = __shfl(wj0, j + 1, 32);
        float w2 = __shfl(wj0, j + 2, 32), w3 = __shfl(wj0, j + 3, 32);
        bf16x4 h0v = *reinterpret_cast<const bf16x4*>(hgat + (long long)s0 * 128 + 4 * lane);
        bf16x4 h1v = *reinterpret_cast<const bf16x4*>(hgat + (long long)s1 * 128 + 4 * lane);
        bf16x4 h2v = *reinterpret_cast<const bf16x4*>(hgat + (long long)s2 * 128 + 4 * lane);
        bf16x4 h3v = *reinterpret_cast<const bf16x4*>(hgat + (long long)s3 * 128 + 4 * lane);
        acc0 = fmaf(w0, b2f(h0v[0]), acc0); acc1 = fmaf(w0, b2f(h0v[1]), acc1);
        acc2 = fmaf(w0, b2f(h0v[2]), acc2); acc3 = fmaf(w0, b2f(h0v[3]), acc3);
        acc0 = fmaf(w1, b2f(h1v[0]), acc0); acc1 = fmaf(w1, b2f(h1v[1]), acc1);
        acc2 = fmaf(w1, b2f(h1v[2]), acc2); acc3 = fmaf(w1, b2f(h1v[3]), acc3);
        acc0 = fmaf(w2, b2f(h2v[0]), acc0); acc1 = fmaf(w2, b2f(h2v[1]), acc1);
        acc2 = fmaf(w2, b2f(h2v[2]), acc2); acc3 = fmaf(w2, b2f(h2v[3]), acc3);
        acc0 = fmaf(w3, b2f(h3v[0]), acc0); acc1 = fmaf(w3, b2f(h3v[1]), acc1);
        acc2 = fmaf(w3, b2f(h3v[2]), acc2); acc3 = fmaf(w3, b2f(h3v[3]), acc3);
    }
    for (int j = 32; j < cn; j += 4) {  // cold tail (deg>32), masked likewise
        int s0 = __shfl(sj1, j - 32, 32), s1 = __shfl(sj1, j - 31, 32);
        int s2 = __shfl(sj1, j - 30, 32), s3 = __shfl(sj1, j - 29, 32);
        float w0 = __shfl(wj1, j - 32, 32), w1 = __shfl(wj1, j - 31, 32);
        float w2 = __shfl(wj1, j - 30, 32), w3 = __shfl(wj1, j - 29, 32);
        bf16x4 h0v = *reinterpret_cast<const bf16x4*>(hgat + (long long)s0 * 128 + 4 * lane);
        bf16x4 h1v = *reinterpret_cast<const bf16x4*>(hgat + (long long)s1 * 128 + 4 * lane);
        bf16x4 h2v = *reinterpret_cast<const bf16x4*>(hgat + (long long)s2 * 128 + 4 * lane);
        bf16x4 h3v = *reinterpret_cast<const bf16x4*>(hgat + (long long)s3 * 128 + 4 * lane);
        acc0 = fmaf(w0, b2f(h0v[0]), acc0); acc1 = fmaf(w0, b2f(h0v[1]), acc1);
        acc2 = fmaf(w0, b2f(h0v[2]), acc2); acc3 = fmaf(w0, b2f(h0v[3]), acc3);
        acc0 = fmaf(w1, b2f(h1v[0]), acc0); acc1 = fmaf(w1, b2f(h1v[1]), acc1);
        acc2 = fmaf(w1, b2f(h1v[2]), acc2); acc3 = fmaf(w1, b2f(h1v[3]), acc3);
        acc0 = fmaf(w2, b2f(h2v[0]), acc0); acc1 = fmaf(w2, b2f(h2v[1]), acc1);
        acc2 = fmaf(w2, b2f(h2v[2]), acc2); acc3 = fmaf(w2, b2f(h2v[3]), acc3);
        acc0 = fmaf(w3, b2f(h3v[0]), acc0); acc1 = fmaf(w3, b2f(h3v[1]), acc1);
        acc2 = fmaf(w3, b2f(h3v[2]), acc2); acc3 = fmaf(w3, b2f(h3v[3]), acc3);
    }
    float inv = 1.0f / den;
    float o0 = acc0 * inv + bg.x + b2f(hl[0]);
    float o1 = acc1 * inv + bg.y + b2f(hl[1]);
    float o2 = acc2 * inv + bg.z + b2f(hl[2]);
    float o3 = acc3 * inv + bg.w + b2f(hl[3]);
    if (relu) {
        o0 = fmaxf(o0, 0.0f); o1 = fmaxf(o1, 0.0f);
        o2 = fmaxf(o2, 0.0f); o3 = fmaxf(o3, 0.0f);
    }
    bf16* orow = out + (long long)d * ldo;
    bf16x4 ov; ov[0] = f2b(o0); ov[1] = f2b(o1); ov[2] = f2b(o2); ov[3] = f2b(o3);
    *reinterpret_cast<bf16x4*>(orow + 4 * lane) = ov;
    if (pert) {
        const float* p = pert_table + (long long)pert[d] * 128;
        if (lane == 0) orow[128] = f2b(ctrl[d]);
        orow[129 + lane] = f2b(p[lane]);
        orow[161 + lane] = f2b(p[32 + lane]);
        orow[193 + lane] = f2b(p[64 + lane]);
        orow[225 + lane] = f2b(p[96 + lane]);
        if (lane < 31) orow[257 + lane] = (bf16)0.0f;
    }
}

// ---------------------------------------------------------------------------
extern "C" void kernel_launch(void* const* d_in, const int* in_sizes, int n_in,
                              void* d_out, int out_size, void* d_ws, size_t ws_size,
                              hipStream_t stream) {
    const int N = in_sizes[0] / 64;   // 100000
    const int E = in_sizes[1] / 2;    // 1000000

    const float* x          = (const float*)d_in[0];
    const int*   ei         = (const int*)d_in[1];
    const int*   e_src      = ei;
    const int*   e_dst      = ei + E;
    const int*   pert       = (const int*)d_in[3];
    const float* ctrl       = (const float*)d_in[4];
    const int*   pos        = (const int*)d_in[5];
    const float* gene_table = (const float*)d_in[6];
    const float* pert_table = (const float*)d_in[7];
    const float* W1   = (const float*)d_in[8];
    const float* a_s1 = (const float*)d_in[9];
    const float* a_d1 = (const float*)d_in[10];
    const float* b1   = (const float*)d_in[11];
    const float* Wl1  = (const float*)d_in[12];
    const float* bl1  = (const float*)d_in[13];
    const float* W2   = (const float*)d_in[14];
    const float* a_s2 = (const float*)d_in[15];
    const float* a_d2 = (const float*)d_in[16];
    const float* b2   = (const float*)d_in[17];
    const float* Wl2  = (const float*)d_in[18];
    const float* bl2  = (const float*)d_in[19];
    const float* Wm1  = (const float*)d_in[20];
    const float* bm1  = (const float*)d_in[21];
    const float* Wm2  = (const float*)d_in[22];
    const float* bm2  = (const float*)d_in[23];

    // workspace layout
    char* ws = (char*)d_ws;
    size_t off = 0;
    auto alloc = [&](size_t bytes) {
        char* p = ws + off;
        off = (off + bytes + 255) & ~(size_t)255;
        return p;
    };
    bf16* hgat   = (bf16*)alloc((size_t)N * 128 * 2);
    bf16* hlin   = (bf16*)alloc((size_t)N * 128 * 2);
    bf16* h0     = (bf16*)alloc((size_t)N * 192 * 2);
    bf16* h1     = (bf16*)alloc((size_t)N * 128 * 2);
    bf16* zbuf   = h0;                                   // z (N x 288) overlays h0+h1 (dead)
    float* asrc  = (float*)alloc((size_t)N * 4);
    float* adst  = (float*)alloc((size_t)N * 4);
    int* cnt     = (int*)alloc((size_t)N * 4);
    int* colidx  = (int*)alloc((size_t)N * CAP * 4);     // padded CSR
    bf16* w1s    = (bf16*)alloc((size_t)3072 * 8 * 2);
    bf16* wl1s   = (bf16*)alloc((size_t)3072 * 8 * 2);
    bf16* w2s    = (bf16*)alloc((size_t)2048 * 8 * 2);
    bf16* wl2s   = (bf16*)alloc((size_t)2048 * 8 * 2);
    bf16* wm1s   = (bf16*)alloc((size_t)2304 * 8 * 2);
    (void)ws_size; (void)n_in; (void)out_size;

    float* out = (float*)d_out;

    const int NBH8 = (N + 7) / 8;        // h0 blocks (8 nodes each)
    const int NBOTH = 49 + NBH8;         // swizzle + h0 blocks
    const int NBSC = (E + 1023) / 1024;  // scatter blocks (4 edges/thr)
    // 1:4 interleave (scatter : other), grid covers both role ranges
    const int NG5 = (NBSC > (NBOTH + 3) / 4) ? NBSC : (NBOTH + 3) / 4;
    const int NBFUSED = NG5 * 5;
    const int NBG64 = (N + 63) / 64;     // column-split dual gemm grid
    const int NBG128 = (N + 127) / 128;  // mlp gemm grid
    dim3 blk(256);
    dim3 gridWave((N + 7) / 8);          // gat: 8 nodes/block (2 per wave)

    // --- cnt = 0 (needed by one-pass CSR scatter) ---
    hipMemsetAsync(cnt, 0, (size_t)N * 4, stream);
    // --- padded-CSR scatter (4 edges/thr, diluted) + weight swizzle + h0 ---
    hipLaunchKernelGGL(h0_prep_kernel, dim3(NBFUSED), blk, 0, stream,
                       x, gene_table, pos, h0, N,
                       W1, Wl1, W2, Wl2, Wm1, w1s, wl1s, w2s, wl2s, wm1s,
                       e_src, e_dst, cnt, colidx, E, NBSC, NBOTH);
    // --- layer 1 linear (dual, col-split) ---
    hipLaunchKernelGGL((gemm_dual_kernel<6>), dim3(NBG64), blk, 0, stream,
                       h0, 192, w1s, wl1s, bl1, hgat, hlin, 128, N,
                       a_s1, a_d1, asrc, adst);
    // --- layer 1 aggregation -> h1 (with relu) ---
    hipLaunchKernelGGL(gat_edge_kernel, gridWave, blk, 0, stream,
                       cnt, colidx, asrc, adst, hgat, hlin, b1, 1, h1, 128, N,
                       (const float*)nullptr, (const float*)nullptr, (const int*)nullptr);
    // --- layer 2 linear (dual, col-split) ---
    hipLaunchKernelGGL((gemm_dual_kernel<4>), dim3(NBG64), blk, 0, stream,
                       h1, 128, w2s, wl2s, bl2, hgat, hlin, 128, N,
                       a_s2, a_d2, asrc, adst);
    // --- layer 2 aggregation -> z[:, 0:128] (stride 288, NO relu) + z-fill ---
    hipLaunchKernelGGL(gat_edge_kernel, gridWave, blk, 0, stream,
                       cnt, colidx, asrc, adst, hgat, hlin, b2, 0, zbuf, 288, N,
                       ctrl, pert_table, pert);
    // --- MLP (both layers fused into one gemm) ---
    hipLaunchKernelGGL((gemm_mlp_kernel<9, 4>), dim3(NBG128), blk, 0, stream,
                       zbuf, 288, wm1s, bm1, N, Wm2, bm2, out);
}

// Round 19
// 377.551 us; speedup vs baseline: 1.1340x; 1.0511x over previous
//
#include <hip/hip_runtime.h>
#include <hip/hip_bf16.h>

typedef __bf16 bf16;
typedef __bf16 bf16x8 __attribute__((ext_vector_type(8)));
typedef __bf16 bf16x4 __attribute__((ext_vector_type(4)));
typedef __bf16 bf16x2 __attribute__((ext_vector_type(2)));
typedef float f32x4 __attribute__((ext_vector_type(4)));

#define CAP 48  // padded-CSR capacity; deg ~ Poisson(10), P(deg>=48) ~ 1e-18/node

__device__ __forceinline__ float b2f(bf16 v) { return (float)v; }
__device__ __forceinline__ bf16 f2b(float v) { return (bf16)v; }

__device__ __forceinline__ float leaky(float x) { return fmaxf(x, 0.2f * x); }

__device__ __forceinline__ bf16x8 zero8() {
    bf16x8 v;
    #pragma unroll
    for (int j = 0; j < 8; ++j) v[j] = (bf16)0.0f;
    return v;
}

// ---------------- weight pre-swizzle into MFMA fragment layout (bf16) ------
// frag f=(kb,nt,ln): dst[f*8+j] = W[kb*32 + (ln>>4)*8 + j][nt*16 + (ln&15)]
__device__ __forceinline__ void swizzle_one(const float* __restrict__ W, bf16* __restrict__ dst,
                                            int f, int NT, int Kreal, int C) {
    int kb = f / (NT * 64);
    int rem = f % (NT * 64);
    int nt = rem / 64;
    int ln = rem % 64;
    int q = ln >> 4, m = ln & 15;
    int c = nt * 16 + m;
    bf16x8 v;
    #pragma unroll
    for (int j = 0; j < 8; ++j) {
        int k = kb * 32 + q * 8 + j;
        v[j] = (k < Kreal) ? f2b(W[k * C + c]) : (bf16)0.0f;
    }
    *reinterpret_cast<bf16x8*>(dst + f * 8) = v;
}

// ---------------- fused: padded-CSR scatter (1:4 interleaved) + prep + h0 --
// Role by blockIdx%5: r==0 -> scatter (1 edge/thread, NT store); r!=0 ->
// first 49 blocks weight swizzle, rest h0 build (8 nodes/block, 32 l/node).
// VERIFIED round-6 config (65us): fine-grained time-spread scatter diluted
// 1:4 with streaming roles is the best measured governor for the
// contention-bound scatter (r11 full-concurrency=90us, r13 concentrated=80us
// both regressed; byte counts flat in all three -> serialization, not BW).
__global__ void h0_prep_kernel(const float* __restrict__ x,
                               const float* __restrict__ gene_table,
                               const int* __restrict__ pos,
                               bf16* __restrict__ h0, int n,
                               const float* __restrict__ W1, const float* __restrict__ Wl1,
                               const float* __restrict__ W2, const float* __restrict__ Wl2,
                               const float* __restrict__ Wm1,
                               bf16* __restrict__ w1s, bf16* __restrict__ wl1s,
                               bf16* __restrict__ w2s, bf16* __restrict__ wl2s,
                               bf16* __restrict__ wm1s,
                               const int* __restrict__ e_src, const int* __restrict__ e_dst,
                               int* __restrict__ cnt, int* __restrict__ colidx,
                               int e, int nbsc, int nboth) {
    int g5 = blockIdx.x / 5, r5 = blockIdx.x % 5;
    if (r5 == 0) {
        if (g5 >= nbsc) return;
        int i = g5 * blockDim.x + threadIdx.x;
        if (i < e) {
            int d = __builtin_nontemporal_load(e_dst + i);
            int s = __builtin_nontemporal_load(e_src + i);
            int k = atomicAdd(&cnt[d], 1);
            if (k < CAP) __builtin_nontemporal_store(s, colidx + d * CAP + k);
        }
        return;
    }
    int ob = g5 * 4 + (r5 - 1);
    if (ob >= nboth) return;
    if (ob < 49) {
        int g = ob * blockDim.x + threadIdx.x;
        if (g < 3072)        swizzle_one(W1,  w1s,  g,          8, 192, 128);
        else if (g < 6144)   swizzle_one(Wl1, wl1s, g - 3072,   8, 192, 128);
        else if (g < 8192)   swizzle_one(W2,  w2s,  g - 6144,   8, 128, 128);
        else if (g < 10240)  swizzle_one(Wl2, wl2s, g - 8192,   8, 128, 128);
        else if (g < 12544)  swizzle_one(Wm1, wm1s, g - 10240,  4, 257,  64);
        return;
    }
    int wid = (ob - 49) * 8 + (threadIdx.x >> 5);
    int l = threadIdx.x & 31;
    if (wid >= n) return;
    const float* g = gene_table + (long long)pos[wid] * 128;
    float4 p = reinterpret_cast<const float4*>(g)[l];
    float ss = p.x * p.x + p.y * p.y + p.z * p.z + p.w * p.w;
    #pragma unroll
    for (int o = 16; o; o >>= 1) ss += __shfl_xor(ss, o);
    float nrm = sqrtf(ss);
    float sc = nrm > 1.0f ? 1.0f / (nrm + 1e-7f) : 1.0f;
    bf16* orow = h0 + (long long)wid * 192;
    float2 xv = reinterpret_cast<const float2*>(x + (long long)wid * 64)[l];
    bf16x2 xb; xb[0] = f2b(xv.x); xb[1] = f2b(xv.y);
    *reinterpret_cast<bf16x2*>(orow + 2 * l) = xb;
    bf16x4 gb;
    gb[0] = f2b(p.x * sc); gb[1] = f2b(p.y * sc);
    gb[2] = f2b(p.z * sc); gb[3] = f2b(p.w * sc);
    *reinterpret_cast<bf16x4*>(orow + 64 + 4 * l) = gb;
}

// ---------------- dual GEMM, column-split across waves ---------------------
// Block (256 thr) covers 64 rows x 128 cols. Wave = (row-half, col-half).
// Dual acc = 64 VGPR/wave. attn logits combined via LDS.
template <int KB>
__global__ __launch_bounds__(256) void gemm_dual_kernel(
    const bf16* __restrict__ A, int lda,
    const bf16* __restrict__ Wg, const bf16* __restrict__ Wl,
    const float* __restrict__ bias_l,
    bf16* __restrict__ outg, bf16* __restrict__ outl, int ldo, int nrows,
    const float* __restrict__ attn_s, const float* __restrict__ attn_d,
    float* __restrict__ asrc, float* __restrict__ adst) {
    const int NTT = 8;  // total col tiles
    __shared__ float sA[64][2];
    int tid = threadIdx.x;
    int wave = tid >> 6, lane = tid & 63;
    int q = lane >> 4, m = lane & 15;
    int nt0 = (wave & 1) * 4;
    long long row_base = (long long)blockIdx.x * 64 + (wave >> 1) * 32;
    long long r0 = row_base + m;
    long long r1 = row_base + 16 + m;
    bool v0 = r0 < nrows, v1 = r1 < nrows;

    f32x4 accg[2][4], accl[2][4];
    #pragma unroll
    for (int t = 0; t < 2; ++t)
        #pragma unroll
        for (int nt = 0; nt < 4; ++nt) {
            f32x4 z = {0.f, 0.f, 0.f, 0.f};
            accg[t][nt] = z; accl[t][nt] = z;
        }

    bf16x8 b0 = v0 ? *reinterpret_cast<const bf16x8*>(A + r0 * lda + q * 8) : zero8();
    bf16x8 b1 = v1 ? *reinterpret_cast<const bf16x8*>(A + r1 * lda + q * 8) : zero8();
    #pragma unroll
    for (int kb = 0; kb < KB; ++kb) {
        bf16x8 nb0, nb1;
        if (kb + 1 < KB) {
            nb0 = v0 ? *reinterpret_cast<const bf16x8*>(A + r0 * lda + (kb + 1) * 32 + q * 8) : zero8();
            nb1 = v1 ? *reinterpret_cast<const bf16x8*>(A + r1 * lda + (kb + 1) * 32 + q * 8) : zero8();
        }
        #pragma unroll
        for (int nt = 0; nt < 4; ++nt) {
            bf16x8 wg = *reinterpret_cast<const bf16x8*>(Wg + ((kb * NTT + nt0 + nt) * 64 + lane) * 8);
            bf16x8 wl = *reinterpret_cast<const bf16x8*>(Wl + ((kb * NTT + nt0 + nt) * 64 + lane) * 8);
            accg[0][nt] = __builtin_amdgcn_mfma_f32_16x16x32_bf16(wg, b0, accg[0][nt], 0, 0, 0);
            accg[1][nt] = __builtin_amdgcn_mfma_f32_16x16x32_bf16(wg, b1, accg[1][nt], 0, 0, 0);
            accl[0][nt] = __builtin_amdgcn_mfma_f32_16x16x32_bf16(wl, b0, accl[0][nt], 0, 0, 0);
            accl[1][nt] = __builtin_amdgcn_mfma_f32_16x16x32_bf16(wl, b1, accl[1][nt], 0, 0, 0);
        }
        b0 = nb0; b1 = nb1;
    }
    #pragma unroll
    for (int t = 0; t < 2; ++t) {
        long long row = t ? r1 : r0;
        if (row < nrows) {
            #pragma unroll
            for (int nt = 0; nt < 4; ++nt) {
                int c0 = (nt0 + nt) * 16 + q * 4;
                bf16x4 og, ol;
                #pragma unroll
                for (int r = 0; r < 4; ++r) {
                    og[r] = f2b(accg[t][nt][r]);
                    ol[r] = f2b(accl[t][nt][r] + bias_l[c0 + r]);
                }
                *reinterpret_cast<bf16x4*>(outg + row * ldo + c0) = og;
                *reinterpret_cast<bf16x4*>(outl + row * ldo + c0) = ol;
            }
        }
    }
    float svt[2], dvt[2];
    #pragma unroll
    for (int t = 0; t < 2; ++t) {
        float sv = 0.f, dv = 0.f;
        #pragma unroll
        for (int nt = 0; nt < 4; ++nt) {
            int c0 = (nt0 + nt) * 16 + q * 4;
            #pragma unroll
            for (int r = 0; r < 4; ++r) {
                float v = accg[t][nt][r];
                sv = fmaf(v, attn_s[c0 + r], sv);
                dv = fmaf(v, attn_d[c0 + r], dv);
            }
        }
        sv += __shfl_xor(sv, 16); sv += __shfl_xor(sv, 32);
        dv += __shfl_xor(dv, 16); dv += __shfl_xor(dv, 32);
        svt[t] = sv; dvt[t] = dv;
        if ((wave & 1) == 0 && q == 0) {
            int rloc = (wave >> 1) * 32 + t * 16 + m;
            sA[rloc][0] = sv; sA[rloc][1] = dv;
        }
    }
    __syncthreads();
    #pragma unroll
    for (int t = 0; t < 2; ++t) {
        long long row = t ? r1 : r0;
        if ((wave & 1) == 1 && q == 0 && row < nrows) {
            int rloc = (wave >> 1) * 32 + t * 16 + m;
            asrc[row] = svt[t] + sA[rloc][0];
            adst[row] = dvt[t] + sA[rloc][1];
        }
    }
}

// ---------------- MLP GEMM: out = relu(relu(A@Wm1+bm1)@Wm2+bm2) ------------
template <int KB, int NT>
__global__ __launch_bounds__(256) void gemm_mlp_kernel(
    const bf16* __restrict__ A, int lda,
    const bf16* __restrict__ Wsw,
    const float* __restrict__ bias, int nrows,
    const float* __restrict__ Wm2, const float* __restrict__ bm2,
    float* __restrict__ out_final) {
    int tid = threadIdx.x;
    int wave = tid >> 6, lane = tid & 63;
    int q = lane >> 4, m = lane & 15;
    long long row_base = (long long)blockIdx.x * 128 + wave * 32;
    long long r0 = row_base + m;
    long long r1 = row_base + 16 + m;
    bool v0 = r0 < nrows, v1 = r1 < nrows;

    f32x4 acc[2][NT];
    #pragma unroll
    for (int t = 0; t < 2; ++t)
        #pragma unroll
        for (int nt = 0; nt < NT; ++nt) {
            f32x4 z = {0.f, 0.f, 0.f, 0.f};
            acc[t][nt] = z;
        }

    bf16x8 b0 = v0 ? *reinterpret_cast<const bf16x8*>(A + r0 * lda + q * 8) : zero8();
    bf16x8 b1 = v1 ? *reinterpret_cast<const bf16x8*>(A + r1 * lda + q * 8) : zero8();
    #pragma unroll
    for (int kb = 0; kb < KB; ++kb) {
        bf16x8 nb0, nb1;
        if (kb + 1 < KB) {
            nb0 = v0 ? *reinterpret_cast<const bf16x8*>(A + r0 * lda + (kb + 1) * 32 + q * 8) : zero8();
            nb1 = v1 ? *reinterpret_cast<const bf16x8*>(A + r1 * lda + (kb + 1) * 32 + q * 8) : zero8();
        }
        #pragma unroll
        for (int nt = 0; nt < NT; ++nt) {
            bf16x8 w = *reinterpret_cast<const bf16x8*>(Wsw + ((kb * NT + nt) * 64 + lane) * 8);
            acc[0][nt] = __builtin_amdgcn_mfma_f32_16x16x32_bf16(w, b0, acc[0][nt], 0, 0, 0);
            acc[1][nt] = __builtin_amdgcn_mfma_f32_16x16x32_bf16(w, b1, acc[1][nt], 0, 0, 0);
        }
        b0 = nb0; b1 = nb1;
    }
    #pragma unroll
    for (int t = 0; t < 2; ++t) {
        float sv = 0.f;
        #pragma unroll
        for (int nt = 0; nt < NT; ++nt) {
            int c0 = nt * 16 + q * 4;
            #pragma unroll
            for (int r = 0; r < 4; ++r) {
                float v = fmaxf(acc[t][nt][r] + bias[c0 + r], 0.0f);
                sv = fmaf(v, Wm2[c0 + r], sv);
            }
        }
        sv += __shfl_xor(sv, 16); sv += __shfl_xor(sv, 32);
        long long row = t ? r1 : r0;
        if (q == 0 && row < nrows) out_final[row] = fmaxf(sv + bm2[0], 0.0f);
    }
}

// ---------------- GAT aggregation: 2 nodes/wave, 32 lanes/node -------------
// Padded CSR (CAP slots/node, cnt[d] valid). Each 32-lane group owns one
// node; lane handles 4 channels (bf16x4 = 8 B loads). Invalid lanes carry
// wj=0 / sj=d, so FULL 4-wide iterations over padded slots are bit-exact.
// __launch_bounds__(256,2): guarantee >=8 waves/SIMD for latency hiding
// (insurance against regalloc creep; kernel is latency-bound gathers).
// colidx via NT load: single-use stream, keep L2 for hot hgat rows + asrc.
__global__ __launch_bounds__(256, 2) void gat_edge_kernel(
                                const int* __restrict__ cnt, const int* __restrict__ colidx,
                                const float* __restrict__ asrc, const float* __restrict__ adst,
                                const bf16* __restrict__ hgat, const bf16* __restrict__ hlin,
                                const float* __restrict__ b_gat, int relu,
                                bf16* __restrict__ out, int ldo, int n,
                                const float* __restrict__ ctrl,
                                const float* __restrict__ pert_table,
                                const int* __restrict__ pert) {
    int d = blockIdx.x * 8 + (threadIdx.x >> 5);
    int lane = threadIdx.x & 31;
    if (d >= n) return;
    float ad = adst[d];
    float e_self = leaky(asrc[d] + ad);
    int cn = cnt[d]; if (cn > CAP) cn = CAP;
    bool val0 = lane < cn;
    bool val1 = lane + 32 < cn;
    int sj0 = val0 ? __builtin_nontemporal_load(colidx + d * CAP + lane) : d;
    int sj1 = val1 ? __builtin_nontemporal_load(colidx + d * CAP + 32 + lane) : d;
    float ej0 = val0 ? leaky(asrc[sj0] + ad) : -1e30f;
    float ej1 = val1 ? leaky(asrc[sj1] + ad) : -1e30f;
    float mx = fmaxf(ej0, ej1);
    #pragma unroll
    for (int o = 16; o; o >>= 1) mx = fmaxf(mx, __shfl_xor(mx, o, 32));
    mx = fmaxf(mx, e_self);
    float wj0 = val0 ? __expf(ej0 - mx) : 0.0f;
    float wj1 = val1 ? __expf(ej1 - mx) : 0.0f;
    float ws = __expf(e_self - mx);
    float sm = wj0 + wj1;
    #pragma unroll
    for (int o = 16; o; o >>= 1) sm += __shfl_xor(sm, o, 32);
    float den = sm + ws;
    // hoist tail operands above the gather loop to overlap their latency
    bf16x4 hl = *reinterpret_cast<const bf16x4*>(hlin + (long long)d * 128 + 4 * lane);
    float4 bg = *reinterpret_cast<const float4*>(b_gat + 4 * lane);
    bf16x4 hd = *reinterpret_cast<const bf16x4*>(hgat + (long long)d * 128 + 4 * lane);
    float acc0 = ws * b2f(hd[0]), acc1 = ws * b2f(hd[1]);
    float acc2 = ws * b2f(hd[2]), acc3 = ws * b2f(hd[3]);
    int c1 = cn < 32 ? cn : 32;
    for (int j = 0; j < c1; j += 4) {  // masked full-width; pad slots add 0
        int s0 = __shfl(sj0, j, 32), s1 = __shfl(sj0, j + 1, 32);
        int s2 = __shfl(sj0, j + 2, 32), s3 = __shfl(sj0, j + 3, 32);
        float w0 = __shfl(wj0, j, 32), w1 = __shfl(wj0, j + 1, 32);
        float w2 = __shfl(wj0, j + 2, 32), w3 = __shfl(wj0, j + 3, 32);
        bf16x4 h0v = *reinterpret_cast<const bf16x4*>(hgat + (long long)s0 * 128 + 4 * lane);
        bf16x4 h1v = *reinterpret_cast<const bf16x4*>(hgat + (long long)s1 * 128 + 4 * lane);
        bf16x4 h2v = *reinterpret_cast<const bf16x4*>(hgat + (long long)s2 * 128 + 4 * lane);
        bf16x4 h3v = *reinterpret_cast<const bf16x4*>(hgat + (long long)s3 * 128 + 4 * lane);
        acc0 = fmaf(w0, b2f(h0v[0]), acc0); acc1 = fmaf(w0, b2f(h0v[1]), acc1);
        acc2 = fmaf(w0, b2f(h0v[2]), acc2); acc3 = fmaf(w0, b2f(h0v[3]), acc3);
        acc0 = fmaf(w1, b2f(h1v[0]), acc0); acc1 = fmaf(w1, b2f(h1v[1]), acc1);
        acc2 = fmaf(w1, b2f(h1v[2]), acc2); acc3 = fmaf(w1, b2f(h1v[3]), acc3);
        acc0 = fmaf(w2, b2f(h2v[0]), acc0); acc1 = fmaf(w2, b2f(h2v[1]), acc1);
        acc2 = fmaf(w2, b2f(h2v[2]), acc2); acc3 = fmaf(w2, b2f(h2v[3]), acc3);
        acc0 = fmaf(w3, b2f(h3v[0]), acc0); acc1 = fmaf(w3, b2f(h3v[1]), acc1);
        acc2 = fmaf(w3, b2f(h3v[2]), acc2); acc3 = fmaf(w3, b2f(h3v[3]), acc3);
    }
    for (int j = 32; j < cn; j += 4) {  // cold tail (deg>32), masked likewise
        int s0 = __shfl(sj1, j - 32, 32), s1 = __shfl(sj1, j - 31, 32);
        int s2 = __shfl(sj1, j - 30, 32), s3 = __shfl(sj1, j - 29, 32);
        float w0 = __shfl(wj1, j - 32, 32), w1 = __shfl(wj1, j - 31, 32);
        float w2 = __shfl(wj1, j - 30, 32), w3 = __shfl(wj1, j - 29, 32);
        bf16x4 h0v = *reinterpret_cast<const bf16x4*>(hgat + (long long)s0 * 128 + 4 * lane);
        bf16x4 h1v = *reinterpret_cast<const bf16x4*>(hgat + (long long)s1 * 128 + 4 * lane);
        bf16x4 h2v = *reinterpret_cast<const bf16x4*>(hgat + (long long)s2 * 128 + 4 * lane);
        bf16x4 h3v = *reinterpret_cast<const bf16x4*>(hgat + (long long)s3 * 128 + 4 * lane);
        acc0 = fmaf(w0, b2f(h0v[0]), acc0); acc1 = fmaf(w0, b2f(h0v[1]), acc1);
        acc2 = fmaf(w0, b2f(h0v[2]), acc2); acc3 = fmaf(w0, b2f(h0v[3]), acc3);
        acc0 = fmaf(w1, b2f(h1v[0]), acc0); acc1 = fmaf(w1, b2f(h1v[1]), acc1);
        acc2 = fmaf(w1, b2f(h1v[2]), acc2); acc3 = fmaf(w1, b2f(h1v[3]), acc3);
        acc0 = fmaf(w2, b2f(h2v[0]), acc0); acc1 = fmaf(w2, b2f(h2v[1]), acc1);
        acc2 = fmaf(w2, b2f(h2v[2]), acc2); acc3 = fmaf(w2, b2f(h2v[3]), acc3);
        acc0 = fmaf(w3, b2f(h3v[0]), acc0); acc1 = fmaf(w3, b2f(h3v[1]), acc1);
        acc2 = fmaf(w3, b2f(h3v[2]), acc2); acc3 = fmaf(w3, b2f(h3v[3]), acc3);
    }
    float inv = 1.0f / den;
    float o0 = acc0 * inv + bg.x + b2f(hl[0]);
    float o1 = acc1 * inv + bg.y + b2f(hl[1]);
    float o2 = acc2 * inv + bg.z + b2f(hl[2]);
    float o3 = acc3 * inv + bg.w + b2f(hl[3]);
    if (relu) {
        o0 = fmaxf(o0, 0.0f); o1 = fmaxf(o1, 0.0f);
        o2 = fmaxf(o2, 0.0f); o3 = fmaxf(o3, 0.0f);
    }
    bf16* orow = out + (long long)d * ldo;
    bf16x4 ov; ov[0] = f2b(o0); ov[1] = f2b(o1); ov[2] = f2b(o2); ov[3] = f2b(o3);
    *reinterpret_cast<bf16x4*>(orow + 4 * lane) = ov;
    if (pert) {
        const float* p = pert_table + (long long)pert[d] * 128;
        if (lane == 0) orow[128] = f2b(ctrl[d]);
        orow[129 + lane] = f2b(p[lane]);
        orow[161 + lane] = f2b(p[32 + lane]);
        orow[193 + lane] = f2b(p[64 + lane]);
        orow[225 + lane] = f2b(p[96 + lane]);
        if (lane < 31) orow[257 + lane] = (bf16)0.0f;
    }
}

// ---------------------------------------------------------------------------
extern "C" void kernel_launch(void* const* d_in, const int* in_sizes, int n_in,
                              void* d_out, int out_size, void* d_ws, size_t ws_size,
                              hipStream_t stream) {
    const int N = in_sizes[0] / 64;   // 100000
    const int E = in_sizes[1] / 2;    // 1000000

    const float* x          = (const float*)d_in[0];
    const int*   ei         = (const int*)d_in[1];
    const int*   e_src      = ei;
    const int*   e_dst      = ei + E;
    const int*   pert       = (const int*)d_in[3];
    const float* ctrl       = (const float*)d_in[4];
    const int*   pos        = (const int*)d_in[5];
    const float* gene_table = (const float*)d_in[6];
    const float* pert_table = (const float*)d_in[7];
    const float* W1   = (const float*)d_in[8];
    const float* a_s1 = (const float*)d_in[9];
    const float* a_d1 = (const float*)d_in[10];
    const float* b1   = (const float*)d_in[11];
    const float* Wl1  = (const float*)d_in[12];
    const float* bl1  = (const float*)d_in[13];
    const float* W2   = (const float*)d_in[14];
    const float* a_s2 = (const float*)d_in[15];
    const float* a_d2 = (const float*)d_in[16];
    const float* b2   = (const float*)d_in[17];
    const float* Wl2  = (const float*)d_in[18];
    const float* bl2  = (const float*)d_in[19];
    const float* Wm1  = (const float*)d_in[20];
    const float* bm1  = (const float*)d_in[21];
    const float* Wm2  = (const float*)d_in[22];
    const float* bm2  = (const float*)d_in[23];

    // workspace layout
    char* ws = (char*)d_ws;
    size_t off = 0;
    auto alloc = [&](size_t bytes) {
        char* p = ws + off;
        off = (off + bytes + 255) & ~(size_t)255;
        return p;
    };
    bf16* hgat   = (bf16*)alloc((size_t)N * 128 * 2);
    bf16* hlin   = (bf16*)alloc((size_t)N * 128 * 2);
    bf16* h0     = (bf16*)alloc((size_t)N * 192 * 2);
    bf16* h1     = (bf16*)alloc((size_t)N * 128 * 2);
    bf16* zbuf   = h0;                                   // z (N x 288) overlays h0+h1 (dead)
    float* asrc  = (float*)alloc((size_t)N * 4);
    float* adst  = (float*)alloc((size_t)N * 4);
    int* cnt     = (int*)alloc((size_t)N * 4);
    int* colidx  = (int*)alloc((size_t)N * CAP * 4);     // padded CSR
    bf16* w1s    = (bf16*)alloc((size_t)3072 * 8 * 2);
    bf16* wl1s   = (bf16*)alloc((size_t)3072 * 8 * 2);
    bf16* w2s    = (bf16*)alloc((size_t)2048 * 8 * 2);
    bf16* wl2s   = (bf16*)alloc((size_t)2048 * 8 * 2);
    bf16* wm1s   = (bf16*)alloc((size_t)2304 * 8 * 2);
    (void)ws_size; (void)n_in; (void)out_size;

    float* out = (float*)d_out;

    const int NBH8 = (N + 7) / 8;        // h0 blocks (8 nodes each)
    const int NBOTH = 49 + NBH8;         // swizzle + h0 blocks
    const int NBSC = (E + 255) / 256;    // padded-CSR scatter blocks (1 edge/thr)
    // 1:4 interleave (scatter : other), grid covers both role ranges
    const int NG5 = (NBSC > (NBOTH + 3) / 4) ? NBSC : (NBOTH + 3) / 4;
    const int NBFUSED = NG5 * 5;
    const int NBG64 = (N + 63) / 64;     // column-split dual gemm grid
    const int NBG128 = (N + 127) / 128;  // mlp gemm grid
    dim3 blk(256);
    dim3 gridWave((N + 7) / 8);          // gat: 8 nodes/block (2 per wave)

    // --- cnt = 0 (needed by one-pass CSR scatter) ---
    hipMemsetAsync(cnt, 0, (size_t)N * 4, stream);
    // --- padded-CSR scatter (interleaved 1:4) + weight pre-swizzle + h0 ---
    hipLaunchKernelGGL(h0_prep_kernel, dim3(NBFUSED), blk, 0, stream,
                       x, gene_table, pos, h0, N,
                       W1, Wl1, W2, Wl2, Wm1, w1s, wl1s, w2s, wl2s, wm1s,
                       e_src, e_dst, cnt, colidx, E, NBSC, NBOTH);
    // --- layer 1 linear (dual, col-split) ---
    hipLaunchKernelGGL((gemm_dual_kernel<6>), dim3(NBG64), blk, 0, stream,
                       h0, 192, w1s, wl1s, bl1, hgat, hlin, 128, N,
                       a_s1, a_d1, asrc, adst);
    // --- layer 1 aggregation -> h1 (with relu) ---
    hipLaunchKernelGGL(gat_edge_kernel, gridWave, blk, 0, stream,
                       cnt, colidx, asrc, adst, hgat, hlin, b1, 1, h1, 128, N,
                       (const float*)nullptr, (const float*)nullptr, (const int*)nullptr);
    // --- layer 2 linear (dual, col-split) ---
    hipLaunchKernelGGL((gemm_dual_kernel<4>), dim3(NBG64), blk, 0, stream,
                       h1, 128, w2s, wl2s, bl2, hgat, hlin, 128, N,
                       a_s2, a_d2, asrc, adst);
    // --- layer 2 aggregation -> z[:, 0:128] (stride 288, NO relu) + z-fill ---
    hipLaunchKernelGGL(gat_edge_kernel, gridWave, blk, 0, stream,
                       cnt, colidx, asrc, adst, hgat, hlin, b2, 0, zbuf, 288, N,
                       ctrl, pert_table, pert);
    // --- MLP (both layers fused into one gemm) ---
    hipLaunchKernelGGL((gemm_mlp_kernel<9, 4>), dim3(NBG128), blk, 0, stream,
                       zbuf, 288, wm1s, bm1, N, Wm2, bm2, out);
}

// Round 21
// 370.501 us; speedup vs baseline: 1.1556x; 1.0190x over previous
//
#include <hip/hip_runtime.h>
#include <hip/hip_bf16.h>

typedef __bf16 bf16;
typedef __bf16 bf16x8 __attribute__((ext_vector_type(8)));
typedef __bf16 bf16x4 __attribute__((ext_vector_type(4)));
typedef __bf16 bf16x2 __attribute__((ext_vector_type(2)));
typedef float f32x4 __attribute__((ext_vector_type(4)));

#define CAP 48  // padded-CSR capacity; deg ~ Poisson(10), P(deg>=48) ~ 1e-18/node

__device__ __forceinline__ float b2f(bf16 v) { return (float)v; }
__device__ __forceinline__ bf16 f2b(float v) { return (bf16)v; }

__device__ __forceinline__ float leaky(float x) { return fmaxf(x, 0.2f * x); }

__device__ __forceinline__ bf16x8 zero8() {
    bf16x8 v;
    #pragma unroll
    for (int j = 0; j < 8; ++j) v[j] = (bf16)0.0f;
    return v;
}

// ---------------- weight pre-swizzle into MFMA fragment layout (bf16) ------
// frag f=(kb,nt,ln): dst[f*8+j] = W[kb*32 + (ln>>4)*8 + j][nt*16 + (ln&15)]
__device__ __forceinline__ void swizzle_one(const float* __restrict__ W, bf16* __restrict__ dst,
                                            int f, int NT, int Kreal, int C) {
    int kb = f / (NT * 64);
    int rem = f % (NT * 64);
    int nt = rem / 64;
    int ln = rem % 64;
    int q = ln >> 4, m = ln & 15;
    int c = nt * 16 + m;
    bf16x8 v;
    #pragma unroll
    for (int j = 0; j < 8; ++j) {
        int k = kb * 32 + q * 8 + j;
        v[j] = (k < Kreal) ? f2b(W[k * C + c]) : (bf16)0.0f;
    }
    *reinterpret_cast<bf16x8*>(dst + f * 8) = v;
}

// ---------------- fused: padded-CSR scatter (1:4 interleaved) + prep + h0 --
// VERIFIED round-6 config (63.5us measured r19): fine-grained time-spread
// scatter diluted 1:4 with streaming roles is the best measured governor for
// the contention-bound scatter (r11 full-concurrency=90us, r13
// concentrated=80us both regressed; byte counts flat -> serialization).
__global__ void h0_prep_kernel(const float* __restrict__ x,
                               const float* __restrict__ gene_table,
                               const int* __restrict__ pos,
                               bf16* __restrict__ h0, int n,
                               const float* __restrict__ W1, const float* __restrict__ Wl1,
                               const float* __restrict__ W2, const float* __restrict__ Wl2,
                               const float* __restrict__ Wm1,
                               bf16* __restrict__ w1s, bf16* __restrict__ wl1s,
                               bf16* __restrict__ w2s, bf16* __restrict__ wl2s,
                               bf16* __restrict__ wm1s,
                               const int* __restrict__ e_src, const int* __restrict__ e_dst,
                               int* __restrict__ cnt, int* __restrict__ colidx,
                               int e, int nbsc, int nboth) {
    int g5 = blockIdx.x / 5, r5 = blockIdx.x % 5;
    if (r5 == 0) {
        if (g5 >= nbsc) return;
        int i = g5 * blockDim.x + threadIdx.x;
        if (i < e) {
            int d = __builtin_nontemporal_load(e_dst + i);
            int s = __builtin_nontemporal_load(e_src + i);
            int k = atomicAdd(&cnt[d], 1);
            if (k < CAP) __builtin_nontemporal_store(s, colidx + d * CAP + k);
        }
        return;
    }
    int ob = g5 * 4 + (r5 - 1);
    if (ob >= nboth) return;
    if (ob < 49) {
        int g = ob * blockDim.x + threadIdx.x;
        if (g < 3072)        swizzle_one(W1,  w1s,  g,          8, 192, 128);
        else if (g < 6144)   swizzle_one(Wl1, wl1s, g - 3072,   8, 192, 128);
        else if (g < 8192)   swizzle_one(W2,  w2s,  g - 6144,   8, 128, 128);
        else if (g < 10240)  swizzle_one(Wl2, wl2s, g - 8192,   8, 128, 128);
        else if (g < 12544)  swizzle_one(Wm1, wm1s, g - 10240,  4, 257,  64);
        return;
    }
    int wid = (ob - 49) * 8 + (threadIdx.x >> 5);
    int l = threadIdx.x & 31;
    if (wid >= n) return;
    const float* g = gene_table + (long long)pos[wid] * 128;
    float4 p = reinterpret_cast<const float4*>(g)[l];
    float ss = p.x * p.x + p.y * p.y + p.z * p.z + p.w * p.w;
    #pragma unroll
    for (int o = 16; o; o >>= 1) ss += __shfl_xor(ss, o);
    float nrm = sqrtf(ss);
    float sc = nrm > 1.0f ? 1.0f / (nrm + 1e-7f) : 1.0f;
    bf16* orow = h0 + (long long)wid * 192;
    float2 xv = reinterpret_cast<const float2*>(x + (long long)wid * 64)[l];
    bf16x2 xb; xb[0] = f2b(xv.x); xb[1] = f2b(xv.y);
    *reinterpret_cast<bf16x2*>(orow + 2 * l) = xb;
    bf16x4 gb;
    gb[0] = f2b(p.x * sc); gb[1] = f2b(p.y * sc);
    gb[2] = f2b(p.z * sc); gb[3] = f2b(p.w * sc);
    *reinterpret_cast<bf16x4*>(orow + 64 + 4 * l) = gb;
}

// ---------------- dual GEMM, column-split across waves ---------------------
// Block (256 thr) covers 64 rows x 128 cols. Wave = (row-half, col-half).
// Dual acc = 64 VGPR/wave. attn logits combined via LDS.
template <int KB>
__global__ __launch_bounds__(256) void gemm_dual_kernel(
    const bf16* __restrict__ A, int lda,
    const bf16* __restrict__ Wg, const bf16* __restrict__ Wl,
    const float* __restrict__ bias_l,
    bf16* __restrict__ outg, bf16* __restrict__ outl, int ldo, int nrows,
    const float* __restrict__ attn_s, const float* __restrict__ attn_d,
    float* __restrict__ asrc, float* __restrict__ adst) {
    const int NTT = 8;  // total col tiles
    __shared__ float sA[64][2];
    int tid = threadIdx.x;
    int wave = tid >> 6, lane = tid & 63;
    int q = lane >> 4, m = lane & 15;
    int nt0 = (wave & 1) * 4;
    long long row_base = (long long)blockIdx.x * 64 + (wave >> 1) * 32;
    long long r0 = row_base + m;
    long long r1 = row_base + 16 + m;
    bool v0 = r0 < nrows, v1 = r1 < nrows;

    f32x4 accg[2][4], accl[2][4];
    #pragma unroll
    for (int t = 0; t < 2; ++t)
        #pragma unroll
        for (int nt = 0; nt < 4; ++nt) {
            f32x4 z = {0.f, 0.f, 0.f, 0.f};
            accg[t][nt] = z; accl[t][nt] = z;
        }

    bf16x8 b0 = v0 ? *reinterpret_cast<const bf16x8*>(A + r0 * lda + q * 8) : zero8();
    bf16x8 b1 = v1 ? *reinterpret_cast<const bf16x8*>(A + r1 * lda + q * 8) : zero8();
    #pragma unroll
    for (int kb = 0; kb < KB; ++kb) {
        bf16x8 nb0, nb1;
        if (kb + 1 < KB) {
            nb0 = v0 ? *reinterpret_cast<const bf16x8*>(A + r0 * lda + (kb + 1) * 32 + q * 8) : zero8();
            nb1 = v1 ? *reinterpret_cast<const bf16x8*>(A + r1 * lda + (kb + 1) * 32 + q * 8) : zero8();
        }
        #pragma unroll
        for (int nt = 0; nt < 4; ++nt) {
            bf16x8 wg = *reinterpret_cast<const bf16x8*>(Wg + ((kb * NTT + nt0 + nt) * 64 + lane) * 8);
            bf16x8 wl = *reinterpret_cast<const bf16x8*>(Wl + ((kb * NTT + nt0 + nt) * 64 + lane) * 8);
            accg[0][nt] = __builtin_amdgcn_mfma_f32_16x16x32_bf16(wg, b0, accg[0][nt], 0, 0, 0);
            accg[1][nt] = __builtin_amdgcn_mfma_f32_16x16x32_bf16(wg, b1, accg[1][nt], 0, 0, 0);
            accl[0][nt] = __builtin_amdgcn_mfma_f32_16x16x32_bf16(wl, b0, accl[0][nt], 0, 0, 0);
            accl[1][nt] = __builtin_amdgcn_mfma_f32_16x16x32_bf16(wl, b1, accl[1][nt], 0, 0, 0);
        }
        b0 = nb0; b1 = nb1;
    }
    #pragma unroll
    for (int t = 0; t < 2; ++t) {
        long long row = t ? r1 : r0;
        if (row < nrows) {
            #pragma unroll
            for (int nt = 0; nt < 4; ++nt) {
                int c0 = (nt0 + nt) * 16 + q * 4;
                bf16x4 og, ol;
                #pragma unroll
                for (int r = 0; r < 4; ++r) {
                    og[r] = f2b(accg[t][nt][r]);
                    ol[r] = f2b(accl[t][nt][r] + bias_l[c0 + r]);
                }
                *reinterpret_cast<bf16x4*>(outg + row * ldo + c0) = og;
                *reinterpret_cast<bf16x4*>(outl + row * ldo + c0) = ol;
            }
        }
    }
    float svt[2], dvt[2];
    #pragma unroll
    for (int t = 0; t < 2; ++t) {
        float sv = 0.f, dv = 0.f;
        #pragma unroll
        for (int nt = 0; nt < 4; ++nt) {
            int c0 = (nt0 + nt) * 16 + q * 4;
            #pragma unroll
            for (int r = 0; r < 4; ++r) {
                float v = accg[t][nt][r];
                sv = fmaf(v, attn_s[c0 + r], sv);
                dv = fmaf(v, attn_d[c0 + r], dv);
            }
        }
        sv += __shfl_xor(sv, 16); sv += __shfl_xor(sv, 32);
        dv += __shfl_xor(dv, 16); dv += __shfl_xor(dv, 32);
        svt[t] = sv; dvt[t] = dv;
        if ((wave & 1) == 0 && q == 0) {
            int rloc = (wave >> 1) * 32 + t * 16 + m;
            sA[rloc][0] = sv; sA[rloc][1] = dv;
        }
    }
    __syncthreads();
    #pragma unroll
    for (int t = 0; t < 2; ++t) {
        long long row = t ? r1 : r0;
        if ((wave & 1) == 1 && q == 0 && row < nrows) {
            int rloc = (wave >> 1) * 32 + t * 16 + m;
            asrc[row] = svt[t] + sA[rloc][0];
            adst[row] = dvt[t] + sA[rloc][1];
        }
    }
}

// ---------------- GAT aggregation (+ optional fused MLP) -------------------
// 2 nodes/wave, 32 lanes/node; padded CSR; masked full-width gather (pad
// slots add 0 exactly). FUSED=1 (layer 2): instead of writing z rows to
// global for a separate MLP kernel, build the 8-node z-tile in LDS
// ([16][296] bf16, 16B-aligned rows; cols 257..287 zeroed since wm1s pads
// k>=257 with 0 and 0*garbage-NaN would poison valid rows) and run the MLP
// in-block: 4 waves x 1 col-tile (16 of 64 cols), 9 MFMAs over K=288 with
// the SAME wm1s fragments + kb-ascending chain as the old gemm_mlp (rows
// 8..15 of the MFMA tile are garbage and only pollute their own discarded
// outputs; MFMA output col j depends only on B col j). Saves the 57.6MB z
// write + 57.6MB read + one dispatch.
template <int FUSED>
__global__ __launch_bounds__(256, 2) void gat_edge_kernel(
                                const int* __restrict__ cnt, const int* __restrict__ colidx,
                                const float* __restrict__ asrc, const float* __restrict__ adst,
                                const bf16* __restrict__ hgat, const bf16* __restrict__ hlin,
                                const float* __restrict__ b_gat, int relu,
                                bf16* __restrict__ out, int ldo, int n,
                                const float* __restrict__ ctrl,
                                const float* __restrict__ pert_table,
                                const int* __restrict__ pert,
                                const bf16* __restrict__ wm1s,
                                const float* __restrict__ bm1,
                                const float* __restrict__ wm2,
                                const float* __restrict__ bm2,
                                float* __restrict__ out_final) {
    __shared__ bf16 zs[16][296];    // fused z-tile (rows 8..15 unused)
    __shared__ float spart[8][4];   // per-node per-wave MLP partials
    int d = blockIdx.x * 8 + (threadIdx.x >> 5);
    int lane = threadIdx.x & 31;
    bool act = d < n;
    if (!FUSED && !act) return;
    int da = act ? d : 0;
    float ad = adst[da];
    float e_self = leaky(asrc[da] + ad);
    int cn = act ? cnt[da] : 0; if (cn > CAP) cn = CAP;
    bool val0 = lane < cn;
    bool val1 = lane + 32 < cn;
    int sj0 = val0 ? __builtin_nontemporal_load(colidx + da * CAP + lane) : da;
    int sj1 = val1 ? __builtin_nontemporal_load(colidx + da * CAP + 32 + lane) : da;
    float ej0 = val0 ? leaky(asrc[sj0] + ad) : -1e30f;
    float ej1 = val1 ? leaky(asrc[sj1] + ad) : -1e30f;
    float mx = fmaxf(ej0, ej1);
    #pragma unroll
    for (int o = 16; o; o >>= 1) mx = fmaxf(mx, __shfl_xor(mx, o, 32));
    mx = fmaxf(mx, e_self);
    float wj0 = val0 ? __expf(ej0 - mx) : 0.0f;
    float wj1 = val1 ? __expf(ej1 - mx) : 0.0f;
    float ws = __expf(e_self - mx);
    float sm = wj0 + wj1;
    #pragma unroll
    for (int o = 16; o; o >>= 1) sm += __shfl_xor(sm, o, 32);
    float den = sm + ws;
    // hoist tail operands above the gather loop to overlap their latency
    bf16x4 hl = *reinterpret_cast<const bf16x4*>(hlin + (long long)da * 128 + 4 * lane);
    float4 bg = *reinterpret_cast<const float4*>(b_gat + 4 * lane);
    bf16x4 hd = *reinterpret_cast<const bf16x4*>(hgat + (long long)da * 128 + 4 * lane);
    float acc0 = ws * b2f(hd[0]), acc1 = ws * b2f(hd[1]);
    float acc2 = ws * b2f(hd[2]), acc3 = ws * b2f(hd[3]);
    int c1 = cn < 32 ? cn : 32;
    for (int j = 0; j < c1; j += 4) {  // masked full-width; pad slots add 0
        int s0 = __shfl(sj0, j, 32), s1 = __shfl(sj0, j + 1, 32);
        int s2 = __shfl(sj0, j + 2, 32), s3 = __shfl(sj0, j + 3, 32);
        float w0 = __shfl(wj0, j, 32), w1 = __shfl(wj0, j + 1, 32);
        float w2 = __shfl(wj0, j + 2, 32), w3 = __shfl(wj0, j + 3, 32);
        bf16x4 h0v = *reinterpret_cast<const bf16x4*>(hgat + (long long)s0 * 128 + 4 * lane);
        bf16x4 h1v = *reinterpret_cast<const bf16x4*>(hgat + (long long)s1 * 128 + 4 * lane);
        bf16x4 h2v = *reinterpret_cast<const bf16x4*>(hgat + (long long)s2 * 128 + 4 * lane);
        bf16x4 h3v = *reinterpret_cast<const bf16x4*>(hgat + (long long)s3 * 128 + 4 * lane);
        acc0 = fmaf(w0, b2f(h0v[0]), acc0); acc1 = fmaf(w0, b2f(h0v[1]), acc1);
        acc2 = fmaf(w0, b2f(h0v[2]), acc2); acc3 = fmaf(w0, b2f(h0v[3]), acc3);
        acc0 = fmaf(w1, b2f(h1v[0]), acc0); acc1 = fmaf(w1, b2f(h1v[1]), acc1);
        acc2 = fmaf(w1, b2f(h1v[2]), acc2); acc3 = fmaf(w1, b2f(h1v[3]), acc3);
        acc0 = fmaf(w2, b2f(h2v[0]), acc0); acc1 = fmaf(w2, b2f(h2v[1]), acc1);
        acc2 = fmaf(w2, b2f(h2v[2]), acc2); acc3 = fmaf(w2, b2f(h2v[3]), acc3);
        acc0 = fmaf(w3, b2f(h3v[0]), acc0); acc1 = fmaf(w3, b2f(h3v[1]), acc1);
        acc2 = fmaf(w3, b2f(h3v[2]), acc2); acc3 = fmaf(w3, b2f(h3v[3]), acc3);
    }
    for (int j = 32; j < cn; j += 4) {  // cold tail (deg>32), masked likewise
        int s0 = __shfl(sj1, j - 32, 32), s1 = __shfl(sj1, j - 31, 32);
        int s2 = __shfl(sj1, j - 30, 32), s3 = __shfl(sj1, j - 29, 32);
        float w0 = __shfl(wj1, j - 32, 32), w1 = __shfl(wj1, j - 31, 32);
        float w2 = __shfl(wj1, j - 30, 32), w3 = __shfl(wj1, j - 29, 32);
        bf16x4 h0v = *reinterpret_cast<const bf16x4*>(hgat + (long long)s0 * 128 + 4 * lane);
        bf16x4 h1v = *reinterpret_cast<const bf16x4*>(hgat + (long long)s1 * 128 + 4 * lane);
        bf16x4 h2v = *reinterpret_cast<const bf16x4*>(hgat + (long long)s2 * 128 + 4 * lane);
        bf16x4 h3v = *reinterpret_cast<const bf16x4*>(hgat + (long long)s3 * 128 + 4 * lane);
        acc0 = fmaf(w0, b2f(h0v[0]), acc0); acc1 = fmaf(w0, b2f(h0v[1]), acc1);
        acc2 = fmaf(w0, b2f(h0v[2]), acc2); acc3 = fmaf(w0, b2f(h0v[3]), acc3);
        acc0 = fmaf(w1, b2f(h1v[0]), acc0); acc1 = fmaf(w1, b2f(h1v[1]), acc1);
        acc2 = fmaf(w1, b2f(h1v[2]), acc2); acc3 = fmaf(w1, b2f(h1v[3]), acc3);
        acc0 = fmaf(w2, b2f(h2v[0]), acc0); acc1 = fmaf(w2, b2f(h2v[1]), acc1);
        acc2 = fmaf(w2, b2f(h2v[2]), acc2); acc3 = fmaf(w2, b2f(h2v[3]), acc3);
        acc0 = fmaf(w3, b2f(h3v[0]), acc0); acc1 = fmaf(w3, b2f(h3v[1]), acc1);
        acc2 = fmaf(w3, b2f(h3v[2]), acc2); acc3 = fmaf(w3, b2f(h3v[3]), acc3);
    }
    float inv = 1.0f / den;
    float o0 = acc0 * inv + bg.x + b2f(hl[0]);
    float o1 = acc1 * inv + bg.y + b2f(hl[1]);
    float o2 = acc2 * inv + bg.z + b2f(hl[2]);
    float o3 = acc3 * inv + bg.w + b2f(hl[3]);
    if (relu) {
        o0 = fmaxf(o0, 0.0f); o1 = fmaxf(o1, 0.0f);
        o2 = fmaxf(o2, 0.0f); o3 = fmaxf(o3, 0.0f);
    }
    if (!FUSED) {
        bf16* orow = out + (long long)da * ldo;
        bf16x4 ov; ov[0] = f2b(o0); ov[1] = f2b(o1); ov[2] = f2b(o2); ov[3] = f2b(o3);
        *reinterpret_cast<bf16x4*>(orow + 4 * lane) = ov;
        if (pert) {
            const float* p = pert_table + (long long)pert[da] * 128;
            if (lane == 0) orow[128] = f2b(ctrl[da]);
            orow[129 + lane] = f2b(p[lane]);
            orow[161 + lane] = f2b(p[32 + lane]);
            orow[193 + lane] = f2b(p[64 + lane]);
            orow[225 + lane] = f2b(p[96 + lane]);
            if (lane < 31) orow[257 + lane] = (bf16)0.0f;
        }
        return;
    }
    // ---- FUSED: build z-tile row in LDS ----
    int dl = threadIdx.x >> 5;  // local node 0..7
    if (act) {
        bf16x4 ov; ov[0] = f2b(o0); ov[1] = f2b(o1); ov[2] = f2b(o2); ov[3] = f2b(o3);
        *reinterpret_cast<bf16x4*>(&zs[dl][4 * lane]) = ov;
        const float* p = pert_table + (long long)pert[da] * 128;
        if (lane == 0) zs[dl][128] = f2b(ctrl[da]);
        zs[dl][129 + lane] = f2b(p[lane]);
        zs[dl][161 + lane] = f2b(p[32 + lane]);
        zs[dl][193 + lane] = f2b(p[64 + lane]);
        zs[dl][225 + lane] = f2b(p[96 + lane]);
        if (lane < 31) zs[dl][257 + lane] = (bf16)0.0f;
    }
    __syncthreads();
    // ---- FUSED: in-block MLP, wave w = col-tile nt=w (16 of 64 cols) ----
    {
        int tid = threadIdx.x;
        int w = tid >> 6;            // wave id = nt
        int lane64 = tid & 63;
        int qq = lane64 >> 4, mm = lane64 & 15;
        f32x4 macc = {0.f, 0.f, 0.f, 0.f};
        #pragma unroll
        for (int kb = 0; kb < 9; ++kb) {
            bf16x8 zf = *reinterpret_cast<const bf16x8*>(&zs[mm][kb * 32 + qq * 8]);
            bf16x8 wf = *reinterpret_cast<const bf16x8*>(wm1s + ((kb * 4 + w) * 64 + lane64) * 8);
            macc = __builtin_amdgcn_mfma_f32_16x16x32_bf16(wf, zf, macc, 0, 0, 0);
        }
        float sv = 0.f;
        int c0 = w * 16 + qq * 4;
        #pragma unroll
        for (int r = 0; r < 4; ++r) {
            float v = fmaxf(macc[r] + bm1[c0 + r], 0.0f);
            sv = fmaf(v, wm2[c0 + r], sv);
        }
        sv += __shfl_xor(sv, 16); sv += __shfl_xor(sv, 32);
        if (qq == 0 && mm < 8) spart[mm][w] = sv;
    }
    __syncthreads();
    if (threadIdx.x < 8) {
        long long dd = (long long)blockIdx.x * 8 + threadIdx.x;
        if (dd < n)
            out_final[dd] = fmaxf(spart[threadIdx.x][0] + spart[threadIdx.x][1] +
                                  spart[threadIdx.x][2] + spart[threadIdx.x][3] + bm2[0], 0.0f);
    }
}

// ---------------------------------------------------------------------------
extern "C" void kernel_launch(void* const* d_in, const int* in_sizes, int n_in,
                              void* d_out, int out_size, void* d_ws, size_t ws_size,
                              hipStream_t stream) {
    const int N = in_sizes[0] / 64;   // 100000
    const int E = in_sizes[1] / 2;    // 1000000

    const float* x          = (const float*)d_in[0];
    const int*   ei         = (const int*)d_in[1];
    const int*   e_src      = ei;
    const int*   e_dst      = ei + E;
    const int*   pert       = (const int*)d_in[3];
    const float* ctrl       = (const float*)d_in[4];
    const int*   pos        = (const int*)d_in[5];
    const float* gene_table = (const float*)d_in[6];
    const float* pert_table = (const float*)d_in[7];
    const float* W1   = (const float*)d_in[8];
    const float* a_s1 = (const float*)d_in[9];
    const float* a_d1 = (const float*)d_in[10];
    const float* b1   = (const float*)d_in[11];
    const float* Wl1  = (const float*)d_in[12];
    const float* bl1  = (const float*)d_in[13];
    const float* W2   = (const float*)d_in[14];
    const float* a_s2 = (const float*)d_in[15];
    const float* a_d2 = (const float*)d_in[16];
    const float* b2   = (const float*)d_in[17];
    const float* Wl2  = (const float*)d_in[18];
    const float* bl2  = (const float*)d_in[19];
    const float* Wm1  = (const float*)d_in[20];
    const float* bm1  = (const float*)d_in[21];
    const float* Wm2  = (const float*)d_in[22];
    const float* bm2  = (const float*)d_in[23];

    // workspace layout
    char* ws = (char*)d_ws;
    size_t off = 0;
    auto alloc = [&](size_t bytes) {
        char* p = ws + off;
        off = (off + bytes + 255) & ~(size_t)255;
        return p;
    };
    bf16* hgat   = (bf16*)alloc((size_t)N * 128 * 2);
    bf16* hlin   = (bf16*)alloc((size_t)N * 128 * 2);
    bf16* h0     = (bf16*)alloc((size_t)N * 192 * 2);
    bf16* h1     = (bf16*)alloc((size_t)N * 128 * 2);
    float* asrc  = (float*)alloc((size_t)N * 4);
    float* adst  = (float*)alloc((size_t)N * 4);
    int* cnt     = (int*)alloc((size_t)N * 4);
    int* colidx  = (int*)alloc((size_t)N * CAP * 4);     // padded CSR
    bf16* w1s    = (bf16*)alloc((size_t)3072 * 8 * 2);
    bf16* wl1s   = (bf16*)alloc((size_t)3072 * 8 * 2);
    bf16* w2s    = (bf16*)alloc((size_t)2048 * 8 * 2);
    bf16* wl2s   = (bf16*)alloc((size_t)2048 * 8 * 2);
    bf16* wm1s   = (bf16*)alloc((size_t)2304 * 8 * 2);
    (void)ws_size; (void)n_in; (void)out_size;

    float* out = (float*)d_out;

    const int NBH8 = (N + 7) / 8;        // h0 blocks (8 nodes each)
    const int NBOTH = 49 + NBH8;         // swizzle + h0 blocks
    const int NBSC = (E + 255) / 256;    // padded-CSR scatter blocks (1 edge/thr)
    // 1:4 interleave (scatter : other), grid covers both role ranges
    const int NG5 = (NBSC > (NBOTH + 3) / 4) ? NBSC : (NBOTH + 3) / 4;
    const int NBFUSED = NG5 * 5;
    const int NBG64 = (N + 63) / 64;     // column-split dual gemm grid
    dim3 blk(256);
    dim3 gridWave((N + 7) / 8);          // gat: 8 nodes/block (2 per wave)

    // --- cnt = 0 (needed by one-pass CSR scatter) ---
    hipMemsetAsync(cnt, 0, (size_t)N * 4, stream);
    // --- padded-CSR scatter (interleaved 1:4) + weight pre-swizzle + h0 ---
    hipLaunchKernelGGL(h0_prep_kernel, dim3(NBFUSED), blk, 0, stream,
                       x, gene_table, pos, h0, N,
                       W1, Wl1, W2, Wl2, Wm1, w1s, wl1s, w2s, wl2s, wm1s,
                       e_src, e_dst, cnt, colidx, E, NBSC, NBOTH);
    // --- layer 1 linear (dual, col-split) ---
    hipLaunchKernelGGL((gemm_dual_kernel<6>), dim3(NBG64), blk, 0, stream,
                       h0, 192, w1s, wl1s, bl1, hgat, hlin, 128, N,
                       a_s1, a_d1, asrc, adst);
    // --- layer 1 aggregation -> h1 (with relu) ---
    hipLaunchKernelGGL((gat_edge_kernel<0>), gridWave, blk, 0, stream,
                       cnt, colidx, asrc, adst, hgat, hlin, b1, 1, h1, 128, N,
                       (const float*)nullptr, (const float*)nullptr, (const int*)nullptr,
                       (const bf16*)nullptr, (const float*)nullptr,
                       (const float*)nullptr, (const float*)nullptr, (float*)nullptr);
    // --- layer 2 linear (dual, col-split) ---
    hipLaunchKernelGGL((gemm_dual_kernel<4>), dim3(NBG64), blk, 0, stream,
                       h1, 128, w2s, wl2s, bl2, hgat, hlin, 128, N,
                       a_s2, a_d2, asrc, adst);
    // --- layer 2 aggregation + FUSED MLP -> out (no z round-trip) ---
    hipLaunchKernelGGL((gat_edge_kernel<1>), gridWave, blk, 0, stream,
                       cnt, colidx, asrc, adst, hgat, hlin, b2, 0, h1, 128, N,
                       ctrl, pert_table, pert,
                       (const bf16*)wm1s, bm1, Wm2, bm2, out);
}